// Round 5
// baseline (5853.502 us; speedup 1.0000x reference)
//
#include <hip/hip_runtime.h>
#include <math.h>

#define NN 50000
#define NE 800000
#define INF 512
#define HID 64
#define OUTF 40
#define NL 16
#define PADN 65

// bucketed CSR build parameters
#define NBLK 256      // edge-blocks; NE = NBLK * EPB exactly
#define EPB 3125
#define NBUK 196      // node buckets of 256 (node >> 8); 196*256 = 50176 >= NN
#define SLEN (NBUK * NBLK)  // 50176 count/offset entries

using short8 = __attribute__((ext_vector_type(8))) short;
using f32x4v = __attribute__((ext_vector_type(4))) float;

// bf16 helpers: RNE pack, cheap unpack
__device__ __forceinline__ unsigned int f2bf(float f) {
    unsigned int u = __float_as_uint(f);
    return (u + 0x7fffu + ((u >> 16) & 1u)) >> 16;
}
__device__ __forceinline__ float bflo(unsigned int w) { return __uint_as_float(w << 16); }
__device__ __forceinline__ float bfhi(unsigned int w) { return __uint_as_float(w & 0xffff0000u); }

// ---------------- bucketed CSR build (no global atomics) ----------------

// per-(bucket, edge-block) counts for dst and src
__global__ __launch_bounds__(256) void k_cnt(const int* __restrict__ src, const int* __restrict__ dst,
                                             int* __restrict__ cntD, int* __restrict__ cntS) {
    __shared__ int hD[NBUK];
    __shared__ int hS[NBUK];
    int t = threadIdx.x;
    int blk = blockIdx.x;
    if (t < NBUK) { hD[t] = 0; hS[t] = 0; }
    __syncthreads();
    int s0 = blk * EPB;
    for (int i = t; i < EPB; i += 256) {
        int e = s0 + i;
        atomicAdd(&hD[dst[e] >> 8], 1);
        atomicAdd(&hS[src[e] >> 8], 1);
    }
    __syncthreads();
    if (t < NBUK) {
        cntD[t * NBLK + blk] = hD[t];
        cntS[t * NBLK + blk] = hS[t];
    }
}

// generic scan trio (Hillis-Steele per block + block-sum fixup), exclusive result in off[]
__global__ __launch_bounds__(256) void gscanA(const int* __restrict__ in, int* __restrict__ incl,
                                              int* __restrict__ bsum, int len) {
    __shared__ int lds[256];
    int i = blockIdx.x * 256 + threadIdx.x;
    int v = (i < len) ? in[i] : 0;
    lds[threadIdx.x] = v;
    __syncthreads();
    for (int off = 1; off < 256; off <<= 1) {
        int t = (threadIdx.x >= off) ? lds[threadIdx.x - off] : 0;
        __syncthreads();
        lds[threadIdx.x] += t;
        __syncthreads();
    }
    if (i < len) incl[i] = lds[threadIdx.x];
    if (threadIdx.x == 255) bsum[blockIdx.x] = lds[255];
}

__global__ __launch_bounds__(256) void gscanB(int* __restrict__ bsum, int nb) {
    __shared__ int lds[256];
    int v = (threadIdx.x < nb) ? bsum[threadIdx.x] : 0;
    lds[threadIdx.x] = v;
    __syncthreads();
    for (int off = 1; off < 256; off <<= 1) {
        int t = (threadIdx.x >= off) ? lds[threadIdx.x - off] : 0;
        __syncthreads();
        lds[threadIdx.x] += t;
        __syncthreads();
    }
    if (threadIdx.x < nb) bsum[threadIdx.x] = lds[threadIdx.x] - v;  // exclusive
}

__global__ __launch_bounds__(256) void gscanC(const int* __restrict__ incl, const int* __restrict__ in,
                                              const int* __restrict__ bsum, int* __restrict__ off, int len) {
    int i = blockIdx.x * 256 + threadIdx.x;
    if (i < len) off[i] = incl[i] - in[i] + bsum[i >> 8];
}

// scatter edges into bucket order: edst[(dst-bucket order)] = (dst,src); esrc[(src-bucket order)] = src.
__global__ __launch_bounds__(256) void k_scat(const int* __restrict__ src, const int* __restrict__ dst,
                                              const int* __restrict__ offD, const int* __restrict__ offS,
                                              uint2* __restrict__ edst, int* __restrict__ esrc) {
    __shared__ int cD[NBUK];
    __shared__ int cS[NBUK];
    int t = threadIdx.x;
    int blk = blockIdx.x;
    if (t < NBUK) { cD[t] = 0; cS[t] = 0; }
    __syncthreads();
    int s0 = blk * EPB;
    for (int i = t; i < EPB; i += 256) {
        int e = s0 + i;
        int d = dst[e];
        int s = src[e];
        int bD = d >> 8;
        int r = atomicAdd(&cD[bD], 1);
        uint2 v;
        v.x = (unsigned)d;
        v.y = (unsigned)s;
        edst[offD[bD * NBLK + blk] + r] = v;
        int bS = s >> 8;
        int r2 = atomicAdd(&cS[bS], 1);
        esrc[offS[bS * NBLK + blk] + r2] = s;
    }
}

// one block per dst-bucket: nd, row_start, epack — all LDS-local.
// epack[p] = (src << 6) | (dst & 63): edge list in CSR order with local dst id.
__global__ __launch_bounds__(256) void k_bcsr(const uint2* __restrict__ edst, const int* __restrict__ offD,
                                              float* __restrict__ nd, int* __restrict__ row_start,
                                              int* __restrict__ epk) {
    __shared__ int cnt[256];
    __shared__ int ex[256];
    __shared__ int cur[256];
    int b = blockIdx.x;
    int t = threadIdx.x;
    int base = offD[b * NBLK];
    int end = (b < NBUK - 1) ? offD[(b + 1) * NBLK] : NE;
    cnt[t] = 0;
    __syncthreads();
    for (int p = base + t; p < end; p += 256) {
        uint2 ed = edst[p];
        atomicAdd(&cnt[ed.x & 255], 1);
    }
    __syncthreads();
    int v = cnt[t];
    ex[t] = v;
    __syncthreads();
    for (int off = 1; off < 256; off <<= 1) {
        int tv = (t >= off) ? ex[t - off] : 0;
        __syncthreads();
        ex[t] += tv;
        __syncthreads();
    }
    int excl = ex[t] - v;
    cur[t] = excl;
    int node = b * 256 + t;
    if (node < NN) {
        nd[node] = 1.0f / sqrtf((float)max(v, 1));
        row_start[node] = base + excl;
    }
    __syncthreads();
    for (int p = base + t; p < end; p += 256) {
        uint2 ed = edst[p];
        int r = atomicAdd(&cur[ed.x & 255], 1);
        epk[base + r] = (int)((ed.y << 6) | (ed.x & 63));
    }
}

// one block per src-bucket: ns only
__global__ __launch_bounds__(256) void k_bns(const int* __restrict__ esrc, const int* __restrict__ offS,
                                             float* __restrict__ ns) {
    __shared__ int cnt[256];
    int b = blockIdx.x;
    int t = threadIdx.x;
    int base = offS[b * NBLK];
    int end = (b < NBUK - 1) ? offS[(b + 1) * NBLK] : NE;
    cnt[t] = 0;
    __syncthreads();
    for (int p = base + t; p < end; p += 256) {
        atomicAdd(&cnt[esrc[p] & 255], 1);
    }
    __syncthreads();
    int node = b * 256 + t;
    if (node < NN) ns[node] = 1.0f / sqrtf((float)max(cnt[t], 1));
}

// ---------------- weight prep ----------------

__global__ __launch_bounds__(256) void k_wprep(const float* __restrict__ W1, const float* __restrict__ W2,
                                               float* __restrict__ w1p, float* __restrict__ w2p) {
    int i = blockIdx.x * 256 + threadIdx.x;
    if (i < NL * HID * HID) {
        int l = i >> 12;
        int rc = i & 4095;
        int r = rc >> 6;
        int c = rc & 63;
        float beta = logf(0.5f / (float)(l + 1) + 1.0f);
        float d = (r == c) ? (1.0f - beta) : 0.0f;
        w1p[i] = beta * W1[i] + d;
        w2p[i] = beta * W2[i] + d;
    }
}

// Win (512x64 fp32, k-major) -> fragment-ordered bf16 for mfma_f32_16x16x32_bf16 B operand.
__global__ __launch_bounds__(256) void k_wfrag(const float* __restrict__ Win, unsigned short* __restrict__ wf) {
    int o = blockIdx.x * 256 + threadIdx.x;
    if (o < 16 * 4 * 64 * 8) {
        int jj = o & 7;
        int l = (o >> 3) & 63;
        int c = (o >> 9) & 3;
        int s = o >> 11;
        int colg = c * 16 + (l & 15);
        int k = s * 32 + ((l >> 4) << 3) + jj;
        wf[o] = (unsigned short)f2bf(Win[k * HID + colg]);
    }
}

// ---------------- h0 GEMM: bf16 MFMA (16x16x32), fragment-ordered LDS, K-split x2 ----------------
__global__ __launch_bounds__(256) void k_gemm0(const float* __restrict__ feat, const unsigned short* __restrict__ wf,
                                               float* __restrict__ p0, float* __restrict__ p1) {
    __shared__ unsigned int fS[2048];  // 8 KB: [s(2)][w(4)][lane(64)][4 uints = 8 bf16]
    int tid = threadIdx.x;
    int lane = tid & 63;
    int wv = tid >> 6;
    int bx = blockIdx.x;
    int w = bx >> 1;
    int kh = bx & 1;
    int nb = w * 64;
    f32x4v acc[4];
#pragma unroll
    for (int c = 0; c < 4; c++) acc[c] = {0.0f, 0.0f, 0.0f, 0.0f};

    int k0 = kh * 256;
    for (int kc = k0; kc < k0 + 256; kc += 64) {
        if (kc != k0) __syncthreads();
        float4 t[4];
#pragma unroll
        for (int j = 0; j < 4; j++) {
            int i = tid + j * 256;
            int nl = i >> 4;
            int k4 = i & 15;
            int n = min(nb + nl, NN - 1);
            t[j] = *(const float4*)(feat + (size_t)n * INF + kc + k4 * 4);
        }
#pragma unroll
        for (int j = 0; j < 4; j++) {
            int i = tid + j * 256;
            int nl = i >> 4;
            int kl = (i & 15) * 4;
            int s = kl >> 5;
            int kk = kl & 31;
            int lslot = (nl & 15) | ((kk >> 3) << 4);
            int dstu = (((s * 4 + (nl >> 4)) * 64 + lslot) << 2) + ((kk & 4) >> 1);
            fS[dstu] = f2bf(t[j].x) | (f2bf(t[j].y) << 16);
            fS[dstu + 1] = f2bf(t[j].z) | (f2bf(t[j].w) << 16);
        }
        __syncthreads();
#pragma unroll
        for (int s = 0; s < 2; ++s) {
            int sg = (kc + s * 32) >> 5;
            short8 af = *(const short8*)&fS[((s * 4 + wv) * 64 + lane) << 2];
            short8 bf[4];
#pragma unroll
            for (int c = 0; c < 4; ++c)
                bf[c] = *(const short8*)(wf + ((size_t)(sg * 4 + c) * 64 + lane) * 8);
#pragma unroll
            for (int c = 0; c < 4; ++c)
                acc[c] = __builtin_amdgcn_mfma_f32_16x16x32_bf16(af, bf[c], acc[c], 0, 0, 0);
        }
    }
    float* p = kh ? p1 : p0;
    int nodeb = nb + (wv << 4) + ((lane >> 4) << 2);
    int colb = lane & 15;
#pragma unroll
    for (int r = 0; r < 4; ++r) {
        int node = nodeb + r;
        if (node < NN) {
            float* pp = p + (size_t)node * HID + colb;
#pragma unroll
            for (int c = 0; c < 4; ++c) pp[c * 16] = acc[c][r];
        }
    }
}

// combine: p0+p1, +bias, relu, ns-scale, bf16 pack -> hs, f0b
__global__ __launch_bounds__(256) void k_gfin(const float* __restrict__ p0, const float* __restrict__ p1,
                                              const float* __restrict__ bin, const float* __restrict__ ns,
                                              unsigned int* __restrict__ hs, unsigned int* __restrict__ f0b) {
    int i = blockIdx.x * 256 + threadIdx.x;
    if (i >= NN * 16) return;
    int node = i >> 4;
    int q = i & 15;
    float4 a = ((const float4*)p0)[i];
    float4 b = ((const float4*)p1)[i];
    float4 bi = ((const float4*)bin)[q];
    float nsv = ns[node];
    float q0 = fmaxf(a.x + b.x + bi.x, 0.0f);
    float q1 = fmaxf(a.y + b.y + bi.y, 0.0f);
    float q2 = fmaxf(a.z + b.z + bi.z, 0.0f);
    float q3 = fmaxf(a.w + b.w + bi.w, 0.0f);
    uint2 pk;
    pk.x = f2bf(q0 * nsv) | (f2bf(q1 * nsv) << 16);
    pk.y = f2bf(q2 * nsv) | (f2bf(q3 * nsv) << 16);
    *(uint2*)(hs + (size_t)node * 32 + q * 2) = pk;
    uint2 pf;
    pf.x = f2bf(q0 * 0.1f) | (f2bf(q1 * 0.1f) << 16);
    pf.y = f2bf(q2 * 0.1f) | (f2bf(q3 * 0.1f) << 16);
    *(uint2*)(f0b + (size_t)node * 32 + q * 2) = pf;
}

// ---------------- fused layer: edge-parallel agg (LDS f32 atomics) + 8-wave matmul ----------------
// 512 threads = 8 waves. Block owns 64 dst-nodes; its CSR edges are contiguous [base,end).
// 8 lanes x 16B = one full 128B row gather per edge per instruction; independent load streams
// (no shfl chains, no per-node chunk waits, no degree stragglers). ds_add_f32 accumulates.
__global__ __launch_bounds__(512) void k_layer(const unsigned int* __restrict__ hs_in, const int* __restrict__ epk,
                                               const int* __restrict__ row_start,
                                               const float* __restrict__ nd, const unsigned int* __restrict__ f0b,
                                               const float* __restrict__ w1p, const float* __restrict__ w2p,
                                               const float* __restrict__ bias, const float* __restrict__ ns,
                                               float* __restrict__ h, unsigned int* __restrict__ hs_out, int write_h) {
    __shared__ float fT[HID * PADN];
    __shared__ float f0T[HID * PADN];
    __shared__ float ndS[64];
    int tid = threadIdx.x;
    int lane = tid & 63;
    int wv = tid >> 6;   // 0..7
    int nb = blockIdx.x * 64;

    // zero accumulator tile
    for (int i = tid; i < HID * PADN; i += 512) fT[i] = 0.0f;
    // stage f0 (bf16) -> LDS transposed fp32
    for (int i = tid; i < 64 * 16; i += 512) {
        int nl = i >> 4;
        int q = i & 15;
        int n = min(nb + nl, NN - 1);
        uint2 v = *(const uint2*)(f0b + (size_t)n * 32 + q * 2);
        f0T[(q * 4 + 0) * PADN + nl] = bflo(v.x);
        f0T[(q * 4 + 1) * PADN + nl] = bfhi(v.x);
        f0T[(q * 4 + 2) * PADN + nl] = bflo(v.y);
        f0T[(q * 4 + 3) * PADN + nl] = bfhi(v.y);
    }
    if (tid < 64) ndS[tid] = nd[min(nb + tid, NN - 1)];
    int base = row_start[nb];
    int end = (nb + 64 < NN) ? row_start[nb + 64] : NE;
    __syncthreads();

    // edge-parallel aggregation: 64 edges per block-iteration, epk software-prefetched
    int j = tid & 7;        // lane-in-edge: owns dims [8j, 8j+8)
    int d0 = j * 8;
    int ep = base + (tid >> 3);
    unsigned int u = 0;
    if (ep < end) u = (unsigned)epk[ep];
    while (ep < end) {
        int epn = ep + 64;
        unsigned int un = 0;
        if (epn < end) un = (unsigned)epk[epn];
        int s = (int)(u >> 6);
        int dl = (int)(u & 63u);
        uint4 v = *(const uint4*)(hs_in + (size_t)s * 32 + j * 4);
        float* fd = fT + d0 * PADN + dl;
        atomicAdd(fd + 0 * PADN, bflo(v.x));
        atomicAdd(fd + 1 * PADN, bfhi(v.x));
        atomicAdd(fd + 2 * PADN, bflo(v.y));
        atomicAdd(fd + 3 * PADN, bfhi(v.y));
        atomicAdd(fd + 4 * PADN, bflo(v.z));
        atomicAdd(fd + 5 * PADN, bfhi(v.z));
        atomicAdd(fd + 6 * PADN, bflo(v.w));
        atomicAdd(fd + 7 * PADN, bfhi(v.w));
        ep = epn;
        u = un;
    }
    __syncthreads();

    // scale by 0.9 * nd[dst]  (consecutive tids -> consecutive LDS addrs, conflict-free)
    for (int i = tid; i < HID * 64; i += 512) {
        int d = i >> 6;
        int nl = i & 63;
        fT[d * PADN + nl] *= 0.9f * ndS[nl];
    }
    __syncthreads();

    // matmul: lane = node, wave = 8-col group; weights wave-uniform -> scalar loads
    int cg = __builtin_amdgcn_readfirstlane(wv) * 8;
    const float* w1b = w1p + cg;
    const float* w2b = w2p + cg;
    float acc[8];
#pragma unroll
    for (int c = 0; c < 8; c++) acc[c] = 0.0f;
    for (int k = 0; k < HID; ++k) {
        float fk = fT[k * PADN + lane];
        float f0k = f0T[k * PADN + lane];
        const float* w1r = w1b + (size_t)k * HID;
        const float* w2r = w2b + (size_t)k * HID;
#pragma unroll
        for (int c = 0; c < 8; c++) acc[c] += fk * w1r[c] + f0k * w2r[c];
    }
    int node = nb + lane;
    if (node < NN) {
        float nsv = ns[node];
        const float* bp = bias + cg;
        float q[8];
#pragma unroll
        for (int c = 0; c < 8; c++) q[c] = fmaxf(acc[c] + bp[c], 0.0f);
        uint2* hsp = (uint2*)(hs_out + (size_t)node * 32 + cg / 2);
#pragma unroll
        for (int c4 = 0; c4 < 2; c4++) {
            uint2 pk;
            pk.x = f2bf(q[c4 * 4 + 0] * nsv) | (f2bf(q[c4 * 4 + 1] * nsv) << 16);
            pk.y = f2bf(q[c4 * 4 + 2] * nsv) | (f2bf(q[c4 * 4 + 3] * nsv) << 16);
            hsp[c4] = pk;
        }
        if (write_h) {
            float4* hp = (float4*)(h + (size_t)node * HID + cg);
            float4 v0 = {q[0], q[1], q[2], q[3]};
            float4 v1 = {q[4], q[5], q[6], q[7]};
            hp[0] = v0;
            hp[1] = v1;
        }
    }
}

// ---------------- output: block = 128 nodes; wave pair splits the 40 cols; LDS lse reduce ----------------
__global__ __launch_bounds__(256) void k_out(const float* __restrict__ h, const float* __restrict__ Wout,
                                             const float* __restrict__ bout, float* __restrict__ out) {
    __shared__ float red_mx[4][64];
    __shared__ float red_s[4][64];
    int tid = threadIdx.x;
    int lane = tid & 63;
    int wv = tid >> 6;
    int half = wv & 1;
    int grp = wv >> 1;
    int node = blockIdx.x * 128 + grp * 64 + lane;
    int nodec = min(node, NN - 1);
    float acc[20];
#pragma unroll
    for (int c = 0; c < 20; c++) acc[c] = 0.0f;
    const float4* hr = (const float4*)(h + (size_t)nodec * HID);
    const float* wb = Wout + half * 20;
    for (int kk = 0; kk < HID / 4; ++kk) {
        float4 a = hr[kk];
        float av[4] = {a.x, a.y, a.z, a.w};
#pragma unroll
        for (int j = 0; j < 4; j++) {
            const float* wr = wb + (size_t)(kk * 4 + j) * OUTF;
#pragma unroll
            for (int c = 0; c < 20; c++) acc[c] += av[j] * wr[c];
        }
    }
    const float* bp = bout + half * 20;
#pragma unroll
    for (int c = 0; c < 20; c++) acc[c] += bp[c];
    float mx = acc[0];
#pragma unroll
    for (int c = 1; c < 20; c++) mx = fmaxf(mx, acc[c]);
    red_mx[wv][lane] = mx;
    __syncthreads();
    float gmx = fmaxf(mx, red_mx[wv ^ 1][lane]);
    float s = 0.0f;
#pragma unroll
    for (int c = 0; c < 20; c++) s += expf(acc[c] - gmx);
    red_s[wv][lane] = s;
    __syncthreads();
    float lse = logf(s + red_s[wv ^ 1][lane]) + gmx;
    if (node < NN) {
        float4* op = (float4*)(out + (size_t)node * OUTF + half * 20);
#pragma unroll
        for (int q = 0; q < 5; q++) {
            float4 v;
            v.x = acc[q * 4 + 0] - lse;
            v.y = acc[q * 4 + 1] - lse;
            v.z = acc[q * 4 + 2] - lse;
            v.w = acc[q * 4 + 3] - lse;
            op[q] = v;
        }
    }
}

extern "C" void kernel_launch(void* const* d_in, const int* in_sizes, int n_in,
                              void* d_out, int out_size, void* d_ws, size_t ws_size,
                              hipStream_t stream) {
    const float* feat = (const float*)d_in[0];
    const float* Win  = (const float*)d_in[1];
    const float* bin  = (const float*)d_in[2];
    const float* W1   = (const float*)d_in[3];
    const float* W2   = (const float*)d_in[4];
    const float* bvec = (const float*)d_in[5];
    const float* Wout = (const float*)d_in[6];
    const float* bout = (const float*)d_in[7];
    const int*   src  = (const int*)d_in[8];
    const int*   dst  = (const int*)d_in[9];
    float* out = (float*)d_out;

    char* ws = (char*)d_ws;
    size_t off = 0;
    auto take = [&](size_t bytes) {
        void* p = ws + off;
        off += (bytes + 255) & ~(size_t)255;
        return p;
    };
    int* bsum      = (int*)take(256 * 4);
    int* row_start = (int*)take(NN * 4);
    int* epk       = (int*)take(NE * 4);
    float* nsrc    = (float*)take(NN * 4);
    float* ndst    = (float*)take(NN * 4);
    int* cntD      = (int*)take(SLEN * 4);
    int* cntS      = (int*)take(SLEN * 4);
    int* offD      = (int*)take(SLEN * 4);
    int* offS      = (int*)take(SLEN * 4);
    int* sincl     = (int*)take(SLEN * 4);
    float* w1p     = (float*)take((size_t)NL * HID * HID * 4);
    float* w2p     = (float*)take((size_t)NL * HID * HID * 4);
    unsigned short* wfrag = (unsigned short*)take((size_t)INF * HID * 2);
    unsigned int* f0b = (unsigned int*)take((size_t)NN * HID * 2);  // bf16
    float* hbuf    = (float*)take((size_t)NN * HID * 4);            // gemm0 partial p0; edst alias
    float* part1   = (float*)take((size_t)NN * HID * 4);            // gemm0 partial p1; esrc alias
    unsigned int* hsA = (unsigned int*)take((size_t)NN * HID * 2);  // bf16
    unsigned int* hsB = (unsigned int*)take((size_t)NN * HID * 2);  // bf16

    // setup-phase aliases (dead before k_gemm0 writes them)
    uint2* edst = (uint2*)hbuf;   // NE * 8B = 6.4 MB <= 12.8 MB
    int* esrc   = (int*)part1;    // NE * 4B = 3.2 MB

    const int NB_W = (NN + 63) / 64;     // 782
    const int NB_O = (NN + 127) / 128;   // 391
    const int NB_S = SLEN / 256;         // 196

    // bucketed CSR build (zero global atomics)
    k_cnt<<<NBLK, 256, 0, stream>>>(src, dst, cntD, cntS);
    gscanA<<<NB_S, 256, 0, stream>>>(cntD, sincl, bsum, SLEN);
    gscanB<<<1, 256, 0, stream>>>(bsum, NB_S);
    gscanC<<<NB_S, 256, 0, stream>>>(sincl, cntD, bsum, offD, SLEN);
    gscanA<<<NB_S, 256, 0, stream>>>(cntS, sincl, bsum, SLEN);
    gscanB<<<1, 256, 0, stream>>>(bsum, NB_S);
    gscanC<<<NB_S, 256, 0, stream>>>(sincl, cntS, bsum, offS, SLEN);
    k_scat<<<NBLK, 256, 0, stream>>>(src, dst, offD, offS, edst, esrc);
    k_bcsr<<<NBUK, 256, 0, stream>>>(edst, offD, ndst, row_start, epk);
    k_bns<<<NBUK, 256, 0, stream>>>(esrc, offS, nsrc);

    k_wprep<<<(NL * HID * HID + 255) / 256, 256, 0, stream>>>(W1, W2, w1p, w2p);
    k_wfrag<<<(INF * HID + 255) / 256, 256, 0, stream>>>(Win, wfrag);
    k_gemm0<<<2 * NB_W, 256, 0, stream>>>(feat, wfrag, hbuf, part1);
    k_gfin<<<(NN * 16 + 255) / 256, 256, 0, stream>>>(hbuf, part1, bin, nsrc, hsA, f0b);

    // ping-pong bf16 hs buffers (gathers read arbitrary rows; in-place would race)
    for (int l = 0; l < NL; ++l) {
        const unsigned int* hin = (l & 1) ? hsB : hsA;
        unsigned int* hout = (l & 1) ? hsA : hsB;
        k_layer<<<NB_W, 512, 0, stream>>>(hin, epk, row_start, ndst, f0b,
                                          w1p + l * HID * HID, w2p + l * HID * HID,
                                          bvec + l * HID, nsrc, hbuf, hout, (l == NL - 1) ? 1 : 0);
    }
    k_out<<<NB_O, 256, 0, stream>>>(hbuf, Wout, bout, out);
}

// Round 6
// 1275.217 us; speedup vs baseline: 4.5902x; 4.5902x over previous
//
#include <hip/hip_runtime.h>
#include <math.h>

#define NN 50000
#define NE 800000
#define INF 512
#define HID 64
#define OUTF 40
#define NL 16
#define PADN 65

// bucketed CSR build parameters
#define NBLK 256      // edge-blocks; NE = NBLK * EPB exactly
#define EPB 3125
#define NBUK 196      // node buckets of 256 (node >> 8); 196*256 = 50176 >= NN
#define SLEN (NBUK * NBLK)  // 50176 count/offset entries

using short8 = __attribute__((ext_vector_type(8))) short;
using f32x4v = __attribute__((ext_vector_type(4))) float;

// bf16 helpers: RNE pack, cheap unpack
__device__ __forceinline__ unsigned int f2bf(float f) {
    unsigned int u = __float_as_uint(f);
    return (u + 0x7fffu + ((u >> 16) & 1u)) >> 16;
}
__device__ __forceinline__ float bflo(unsigned int w) { return __uint_as_float(w << 16); }
__device__ __forceinline__ float bfhi(unsigned int w) { return __uint_as_float(w & 0xffff0000u); }

// ---------------- bucketed CSR build (no global atomics) ----------------

__global__ __launch_bounds__(256) void k_cnt(const int* __restrict__ src, const int* __restrict__ dst,
                                             int* __restrict__ cntD, int* __restrict__ cntS) {
    __shared__ int hD[NBUK];
    __shared__ int hS[NBUK];
    int t = threadIdx.x;
    int blk = blockIdx.x;
    if (t < NBUK) { hD[t] = 0; hS[t] = 0; }
    __syncthreads();
    int s0 = blk * EPB;
    for (int i = t; i < EPB; i += 256) {
        int e = s0 + i;
        atomicAdd(&hD[dst[e] >> 8], 1);
        atomicAdd(&hS[src[e] >> 8], 1);
    }
    __syncthreads();
    if (t < NBUK) {
        cntD[t * NBLK + blk] = hD[t];
        cntS[t * NBLK + blk] = hS[t];
    }
}

__global__ __launch_bounds__(256) void gscanA(const int* __restrict__ in, int* __restrict__ incl,
                                              int* __restrict__ bsum, int len) {
    __shared__ int lds[256];
    int i = blockIdx.x * 256 + threadIdx.x;
    int v = (i < len) ? in[i] : 0;
    lds[threadIdx.x] = v;
    __syncthreads();
    for (int off = 1; off < 256; off <<= 1) {
        int t = (threadIdx.x >= off) ? lds[threadIdx.x - off] : 0;
        __syncthreads();
        lds[threadIdx.x] += t;
        __syncthreads();
    }
    if (i < len) incl[i] = lds[threadIdx.x];
    if (threadIdx.x == 255) bsum[blockIdx.x] = lds[255];
}

__global__ __launch_bounds__(256) void gscanB(int* __restrict__ bsum, int nb) {
    __shared__ int lds[256];
    int v = (threadIdx.x < nb) ? bsum[threadIdx.x] : 0;
    lds[threadIdx.x] = v;
    __syncthreads();
    for (int off = 1; off < 256; off <<= 1) {
        int t = (threadIdx.x >= off) ? lds[threadIdx.x - off] : 0;
        __syncthreads();
        lds[threadIdx.x] += t;
        __syncthreads();
    }
    if (threadIdx.x < nb) bsum[threadIdx.x] = lds[threadIdx.x] - v;  // exclusive
}

__global__ __launch_bounds__(256) void gscanC(const int* __restrict__ incl, const int* __restrict__ in,
                                              const int* __restrict__ bsum, int* __restrict__ off, int len) {
    int i = blockIdx.x * 256 + threadIdx.x;
    if (i < len) off[i] = incl[i] - in[i] + bsum[i >> 8];
}

__global__ __launch_bounds__(256) void k_scat(const int* __restrict__ src, const int* __restrict__ dst,
                                              const int* __restrict__ offD, const int* __restrict__ offS,
                                              uint2* __restrict__ edst, int* __restrict__ esrc) {
    __shared__ int cD[NBUK];
    __shared__ int cS[NBUK];
    int t = threadIdx.x;
    int blk = blockIdx.x;
    if (t < NBUK) { cD[t] = 0; cS[t] = 0; }
    __syncthreads();
    int s0 = blk * EPB;
    for (int i = t; i < EPB; i += 256) {
        int e = s0 + i;
        int d = dst[e];
        int s = src[e];
        int bD = d >> 8;
        int r = atomicAdd(&cD[bD], 1);
        uint2 v;
        v.x = (unsigned)d;
        v.y = (unsigned)s;
        edst[offD[bD * NBLK + blk] + r] = v;
        int bS = s >> 8;
        int r2 = atomicAdd(&cS[bS], 1);
        esrc[offS[bS * NBLK + blk] + r2] = s;
    }
}

// one block per dst-bucket: nd, row_start, epack — all LDS-local.
// epack[p] = (src << 6) | (dst & 63): edge list in CSR order with local dst id.
__global__ __launch_bounds__(256) void k_bcsr(const uint2* __restrict__ edst, const int* __restrict__ offD,
                                              float* __restrict__ nd, int* __restrict__ row_start,
                                              int* __restrict__ epk) {
    __shared__ int cnt[256];
    __shared__ int ex[256];
    __shared__ int cur[256];
    int b = blockIdx.x;
    int t = threadIdx.x;
    int base = offD[b * NBLK];
    int end = (b < NBUK - 1) ? offD[(b + 1) * NBLK] : NE;
    cnt[t] = 0;
    __syncthreads();
    for (int p = base + t; p < end; p += 256) {
        uint2 ed = edst[p];
        atomicAdd(&cnt[ed.x & 255], 1);
    }
    __syncthreads();
    int v = cnt[t];
    ex[t] = v;
    __syncthreads();
    for (int off = 1; off < 256; off <<= 1) {
        int tv = (t >= off) ? ex[t - off] : 0;
        __syncthreads();
        ex[t] += tv;
        __syncthreads();
    }
    int excl = ex[t] - v;
    cur[t] = excl;
    int node = b * 256 + t;
    if (node < NN) {
        nd[node] = 1.0f / sqrtf((float)max(v, 1));
        row_start[node] = base + excl;
    }
    __syncthreads();
    for (int p = base + t; p < end; p += 256) {
        uint2 ed = edst[p];
        int r = atomicAdd(&cur[ed.x & 255], 1);
        epk[base + r] = (int)((ed.y << 6) | (ed.x & 63));
    }
}

__global__ __launch_bounds__(256) void k_bns(const int* __restrict__ esrc, const int* __restrict__ offS,
                                             float* __restrict__ ns) {
    __shared__ int cnt[256];
    int b = blockIdx.x;
    int t = threadIdx.x;
    int base = offS[b * NBLK];
    int end = (b < NBUK - 1) ? offS[(b + 1) * NBLK] : NE;
    cnt[t] = 0;
    __syncthreads();
    for (int p = base + t; p < end; p += 256) {
        atomicAdd(&cnt[esrc[p] & 255], 1);
    }
    __syncthreads();
    int node = b * 256 + t;
    if (node < NN) ns[node] = 1.0f / sqrtf((float)max(cnt[t], 1));
}

// ---------------- weight prep ----------------

__global__ __launch_bounds__(256) void k_wprep(const float* __restrict__ W1, const float* __restrict__ W2,
                                               float* __restrict__ w1p, float* __restrict__ w2p) {
    int i = blockIdx.x * 256 + threadIdx.x;
    if (i < NL * HID * HID) {
        int l = i >> 12;
        int rc = i & 4095;
        int r = rc >> 6;
        int c = rc & 63;
        float beta = logf(0.5f / (float)(l + 1) + 1.0f);
        float d = (r == c) ? (1.0f - beta) : 0.0f;
        w1p[i] = beta * W1[i] + d;
        w2p[i] = beta * W2[i] + d;
    }
}

// Win (512x64 fp32, k-major) -> fragment-ordered bf16 for mfma_f32_16x16x32_bf16 B operand.
__global__ __launch_bounds__(256) void k_wfrag(const float* __restrict__ Win, unsigned short* __restrict__ wf) {
    int o = blockIdx.x * 256 + threadIdx.x;
    if (o < 16 * 4 * 64 * 8) {
        int jj = o & 7;
        int l = (o >> 3) & 63;
        int c = (o >> 9) & 3;
        int s = o >> 11;
        int colg = c * 16 + (l & 15);
        int k = s * 32 + ((l >> 4) << 3) + jj;
        wf[o] = (unsigned short)f2bf(Win[k * HID + colg]);
    }
}

// ---------------- h0 GEMM: bf16 MFMA (16x16x32), fragment-ordered LDS, K-split x2 ----------------
__global__ __launch_bounds__(256) void k_gemm0(const float* __restrict__ feat, const unsigned short* __restrict__ wf,
                                               float* __restrict__ p0, float* __restrict__ p1) {
    __shared__ unsigned int fS[2048];  // 8 KB: [s(2)][w(4)][lane(64)][4 uints = 8 bf16]
    int tid = threadIdx.x;
    int lane = tid & 63;
    int wv = tid >> 6;
    int bx = blockIdx.x;
    int w = bx >> 1;
    int kh = bx & 1;
    int nb = w * 64;
    f32x4v acc[4];
#pragma unroll
    for (int c = 0; c < 4; c++) acc[c] = {0.0f, 0.0f, 0.0f, 0.0f};

    int k0 = kh * 256;
    for (int kc = k0; kc < k0 + 256; kc += 64) {
        if (kc != k0) __syncthreads();
        float4 t[4];
#pragma unroll
        for (int j = 0; j < 4; j++) {
            int i = tid + j * 256;
            int nl = i >> 4;
            int k4 = i & 15;
            int n = min(nb + nl, NN - 1);
            t[j] = *(const float4*)(feat + (size_t)n * INF + kc + k4 * 4);
        }
#pragma unroll
        for (int j = 0; j < 4; j++) {
            int i = tid + j * 256;
            int nl = i >> 4;
            int kl = (i & 15) * 4;
            int s = kl >> 5;
            int kk = kl & 31;
            int lslot = (nl & 15) | ((kk >> 3) << 4);
            int dstu = (((s * 4 + (nl >> 4)) * 64 + lslot) << 2) + ((kk & 4) >> 1);
            fS[dstu] = f2bf(t[j].x) | (f2bf(t[j].y) << 16);
            fS[dstu + 1] = f2bf(t[j].z) | (f2bf(t[j].w) << 16);
        }
        __syncthreads();
#pragma unroll
        for (int s = 0; s < 2; ++s) {
            int sg = (kc + s * 32) >> 5;
            short8 af = *(const short8*)&fS[((s * 4 + wv) * 64 + lane) << 2];
            short8 bf[4];
#pragma unroll
            for (int c = 0; c < 4; ++c)
                bf[c] = *(const short8*)(wf + ((size_t)(sg * 4 + c) * 64 + lane) * 8);
#pragma unroll
            for (int c = 0; c < 4; ++c)
                acc[c] = __builtin_amdgcn_mfma_f32_16x16x32_bf16(af, bf[c], acc[c], 0, 0, 0);
        }
    }
    float* p = kh ? p1 : p0;
    int nodeb = nb + (wv << 4) + ((lane >> 4) << 2);
    int colb = lane & 15;
#pragma unroll
    for (int r = 0; r < 4; ++r) {
        int node = nodeb + r;
        if (node < NN) {
            float* pp = p + (size_t)node * HID + colb;
#pragma unroll
            for (int c = 0; c < 4; ++c) pp[c * 16] = acc[c][r];
        }
    }
}

// combine: p0+p1, +bias, relu, ns-scale, bf16 pack -> hs, f0b
__global__ __launch_bounds__(256) void k_gfin(const float* __restrict__ p0, const float* __restrict__ p1,
                                              const float* __restrict__ bin, const float* __restrict__ ns,
                                              unsigned int* __restrict__ hs, unsigned int* __restrict__ f0b) {
    int i = blockIdx.x * 256 + threadIdx.x;
    if (i >= NN * 16) return;
    int node = i >> 4;
    int q = i & 15;
    float4 a = ((const float4*)p0)[i];
    float4 b = ((const float4*)p1)[i];
    float4 bi = ((const float4*)bin)[q];
    float nsv = ns[node];
    float q0 = fmaxf(a.x + b.x + bi.x, 0.0f);
    float q1 = fmaxf(a.y + b.y + bi.y, 0.0f);
    float q2 = fmaxf(a.z + b.z + bi.z, 0.0f);
    float q3 = fmaxf(a.w + b.w + bi.w, 0.0f);
    uint2 pk;
    pk.x = f2bf(q0 * nsv) | (f2bf(q1 * nsv) << 16);
    pk.y = f2bf(q2 * nsv) | (f2bf(q3 * nsv) << 16);
    *(uint2*)(hs + (size_t)node * 32 + q * 2) = pk;
    uint2 pf;
    pf.x = f2bf(q0 * 0.1f) | (f2bf(q1 * 0.1f) << 16);
    pf.y = f2bf(q2 * 0.1f) | (f2bf(q3 * 0.1f) << 16);
    *(uint2*)(f0b + (size_t)node * 32 + q * 2) = pf;
}

// ---------------- fused layer: slot-run edge aggregation (register accumulate, rare LDS-atomic flush) ----------------
// 512 threads = 8 waves. Block owns 64 dst-nodes; CSR edges contiguous [base,end).
// 64 slots x 8 lanes; slot s owns a CONTIGUOUS slice of ~len edges (dst-sorted -> ~2 distinct nodes).
// Lane j accumulates dims [8j,8j+8) in registers across the run; flushes to fT via atomicAdd only at
// dst-change (~2.3 flushes/slice vs per-edge atomics -> no same-address contention, 7x fewer atomics).
__global__ __launch_bounds__(512) void k_layer(const unsigned int* __restrict__ hs_in, const int* __restrict__ epk,
                                               const int* __restrict__ row_start,
                                               const float* __restrict__ nd, const unsigned int* __restrict__ f0b,
                                               const float* __restrict__ w1p, const float* __restrict__ w2p,
                                               const float* __restrict__ bias, const float* __restrict__ ns,
                                               float* __restrict__ h, unsigned int* __restrict__ hs_out, int write_h) {
    __shared__ float fT[HID * PADN];
    __shared__ float f0T[HID * PADN];
    __shared__ float ndS[64];
    int tid = threadIdx.x;
    int lane = tid & 63;
    int wv = tid >> 6;   // 0..7
    int nb = blockIdx.x * 64;

    // zero accumulator tile
    for (int i = tid; i < HID * PADN; i += 512) fT[i] = 0.0f;
    // stage f0 (bf16) -> LDS transposed fp32
    for (int i = tid; i < 64 * 16; i += 512) {
        int nl = i >> 4;
        int q = i & 15;
        int n = min(nb + nl, NN - 1);
        uint2 v = *(const uint2*)(f0b + (size_t)n * 32 + q * 2);
        f0T[(q * 4 + 0) * PADN + nl] = bflo(v.x);
        f0T[(q * 4 + 1) * PADN + nl] = bfhi(v.x);
        f0T[(q * 4 + 2) * PADN + nl] = bflo(v.y);
        f0T[(q * 4 + 3) * PADN + nl] = bfhi(v.y);
    }
    if (tid < 64) ndS[tid] = nd[min(nb + tid, NN - 1)];
    int base = row_start[nb];
    int end = (nb + 64 < NN) ? row_start[nb + 64] : NE;
    __syncthreads();

    // slot-run aggregation
    int slot = tid >> 3;   // 0..63
    int j = tid & 7;       // lane-in-slot: owns dims [8j, 8j+8)
    int d0 = j * 8;
    int E = end - base;
    int len = (E + 63) >> 6;
    int e0 = base + slot * len;
    int e1 = min(e0 + len, end);
    float a0 = 0.f, a1 = 0.f, a2 = 0.f, a3 = 0.f, a4 = 0.f, a5 = 0.f, a6 = 0.f, a7 = 0.f;
    int cur = -1;
    for (int e = e0; e < e1; ++e) {
        unsigned int u = (unsigned)epk[e];
        int s = (int)(u >> 6);
        int dl = (int)(u & 63u);
        if (dl != cur) {
            if (cur >= 0) {
                float* fd = fT + d0 * PADN + cur;
                atomicAdd(fd + 0 * PADN, a0);
                atomicAdd(fd + 1 * PADN, a1);
                atomicAdd(fd + 2 * PADN, a2);
                atomicAdd(fd + 3 * PADN, a3);
                atomicAdd(fd + 4 * PADN, a4);
                atomicAdd(fd + 5 * PADN, a5);
                atomicAdd(fd + 6 * PADN, a6);
                atomicAdd(fd + 7 * PADN, a7);
            }
            a0 = a1 = a2 = a3 = a4 = a5 = a6 = a7 = 0.f;
            cur = dl;
        }
        uint4 v = *(const uint4*)(hs_in + (size_t)s * 32 + j * 4);
        a0 += bflo(v.x);
        a1 += bfhi(v.x);
        a2 += bflo(v.y);
        a3 += bfhi(v.y);
        a4 += bflo(v.z);
        a5 += bfhi(v.z);
        a6 += bflo(v.w);
        a7 += bfhi(v.w);
    }
    if (cur >= 0) {
        float* fd = fT + d0 * PADN + cur;
        atomicAdd(fd + 0 * PADN, a0);
        atomicAdd(fd + 1 * PADN, a1);
        atomicAdd(fd + 2 * PADN, a2);
        atomicAdd(fd + 3 * PADN, a3);
        atomicAdd(fd + 4 * PADN, a4);
        atomicAdd(fd + 5 * PADN, a5);
        atomicAdd(fd + 6 * PADN, a6);
        atomicAdd(fd + 7 * PADN, a7);
    }
    __syncthreads();

    // scale by 0.9 * nd[dst]  (consecutive tids -> consecutive LDS addrs, conflict-free)
    for (int i = tid; i < HID * 64; i += 512) {
        int d = i >> 6;
        int nl = i & 63;
        fT[d * PADN + nl] *= 0.9f * ndS[nl];
    }
    __syncthreads();

    // matmul: lane = node, wave = 8-col group; weights wave-uniform -> scalar loads
    int cg = __builtin_amdgcn_readfirstlane(wv) * 8;
    const float* w1b = w1p + cg;
    const float* w2b = w2p + cg;
    float acc[8];
#pragma unroll
    for (int c = 0; c < 8; c++) acc[c] = 0.0f;
    for (int k = 0; k < HID; ++k) {
        float fk = fT[k * PADN + lane];
        float f0k = f0T[k * PADN + lane];
        const float* w1r = w1b + (size_t)k * HID;
        const float* w2r = w2b + (size_t)k * HID;
#pragma unroll
        for (int c = 0; c < 8; c++) acc[c] += fk * w1r[c] + f0k * w2r[c];
    }
    int node = nb + lane;
    if (node < NN) {
        float nsv = ns[node];
        const float* bp = bias + cg;
        float q[8];
#pragma unroll
        for (int c = 0; c < 8; c++) q[c] = fmaxf(acc[c] + bp[c], 0.0f);
        uint2* hsp = (uint2*)(hs_out + (size_t)node * 32 + cg / 2);
#pragma unroll
        for (int c4 = 0; c4 < 2; c4++) {
            uint2 pk;
            pk.x = f2bf(q[c4 * 4 + 0] * nsv) | (f2bf(q[c4 * 4 + 1] * nsv) << 16);
            pk.y = f2bf(q[c4 * 4 + 2] * nsv) | (f2bf(q[c4 * 4 + 3] * nsv) << 16);
            hsp[c4] = pk;
        }
        if (write_h) {
            float4* hp = (float4*)(h + (size_t)node * HID + cg);
            float4 v0 = {q[0], q[1], q[2], q[3]};
            float4 v1 = {q[4], q[5], q[6], q[7]};
            hp[0] = v0;
            hp[1] = v1;
        }
    }
}

// ---------------- output: block = 128 nodes; wave pair splits the 40 cols; LDS lse reduce ----------------
__global__ __launch_bounds__(256) void k_out(const float* __restrict__ h, const float* __restrict__ Wout,
                                             const float* __restrict__ bout, float* __restrict__ out) {
    __shared__ float red_mx[4][64];
    __shared__ float red_s[4][64];
    int tid = threadIdx.x;
    int lane = tid & 63;
    int wv = tid >> 6;
    int half = wv & 1;
    int grp = wv >> 1;
    int node = blockIdx.x * 128 + grp * 64 + lane;
    int nodec = min(node, NN - 1);
    float acc[20];
#pragma unroll
    for (int c = 0; c < 20; c++) acc[c] = 0.0f;
    const float4* hr = (const float4*)(h + (size_t)nodec * HID);
    const float* wb = Wout + half * 20;
    for (int kk = 0; kk < HID / 4; ++kk) {
        float4 a = hr[kk];
        float av[4] = {a.x, a.y, a.z, a.w};
#pragma unroll
        for (int j = 0; j < 4; j++) {
            const float* wr = wb + (size_t)(kk * 4 + j) * OUTF;
#pragma unroll
            for (int c = 0; c < 20; c++) acc[c] += av[j] * wr[c];
        }
    }
    const float* bp = bout + half * 20;
#pragma unroll
    for (int c = 0; c < 20; c++) acc[c] += bp[c];
    float mx = acc[0];
#pragma unroll
    for (int c = 1; c < 20; c++) mx = fmaxf(mx, acc[c]);
    red_mx[wv][lane] = mx;
    __syncthreads();
    float gmx = fmaxf(mx, red_mx[wv ^ 1][lane]);
    float s = 0.0f;
#pragma unroll
    for (int c = 0; c < 20; c++) s += expf(acc[c] - gmx);
    red_s[wv][lane] = s;
    __syncthreads();
    float lse = logf(s + red_s[wv ^ 1][lane]) + gmx;
    if (node < NN) {
        float4* op = (float4*)(out + (size_t)node * OUTF + half * 20);
#pragma unroll
        for (int q = 0; q < 5; q++) {
            float4 v;
            v.x = acc[q * 4 + 0] - lse;
            v.y = acc[q * 4 + 1] - lse;
            v.z = acc[q * 4 + 2] - lse;
            v.w = acc[q * 4 + 3] - lse;
            op[q] = v;
        }
    }
}

extern "C" void kernel_launch(void* const* d_in, const int* in_sizes, int n_in,
                              void* d_out, int out_size, void* d_ws, size_t ws_size,
                              hipStream_t stream) {
    const float* feat = (const float*)d_in[0];
    const float* Win  = (const float*)d_in[1];
    const float* bin  = (const float*)d_in[2];
    const float* W1   = (const float*)d_in[3];
    const float* W2   = (const float*)d_in[4];
    const float* bvec = (const float*)d_in[5];
    const float* Wout = (const float*)d_in[6];
    const float* bout = (const float*)d_in[7];
    const int*   src  = (const int*)d_in[8];
    const int*   dst  = (const int*)d_in[9];
    float* out = (float*)d_out;

    char* ws = (char*)d_ws;
    size_t off = 0;
    auto take = [&](size_t bytes) {
        void* p = ws + off;
        off += (bytes + 255) & ~(size_t)255;
        return p;
    };
    int* bsum      = (int*)take(256 * 4);
    int* row_start = (int*)take(NN * 4);
    int* epk       = (int*)take(NE * 4);
    float* nsrc    = (float*)take(NN * 4);
    float* ndst    = (float*)take(NN * 4);
    int* cntD      = (int*)take(SLEN * 4);
    int* cntS      = (int*)take(SLEN * 4);
    int* offD      = (int*)take(SLEN * 4);
    int* offS      = (int*)take(SLEN * 4);
    int* sincl     = (int*)take(SLEN * 4);
    float* w1p     = (float*)take((size_t)NL * HID * HID * 4);
    float* w2p     = (float*)take((size_t)NL * HID * HID * 4);
    unsigned short* wfrag = (unsigned short*)take((size_t)INF * HID * 2);
    unsigned int* f0b = (unsigned int*)take((size_t)NN * HID * 2);  // bf16
    float* hbuf    = (float*)take((size_t)NN * HID * 4);            // gemm0 partial p0; edst alias
    float* part1   = (float*)take((size_t)NN * HID * 4);            // gemm0 partial p1; esrc alias
    unsigned int* hsA = (unsigned int*)take((size_t)NN * HID * 2);  // bf16
    unsigned int* hsB = (unsigned int*)take((size_t)NN * HID * 2);  // bf16

    // setup-phase aliases (dead before k_gemm0 writes them)
    uint2* edst = (uint2*)hbuf;   // NE * 8B = 6.4 MB <= 12.8 MB
    int* esrc   = (int*)part1;    // NE * 4B = 3.2 MB

    const int NB_W = (NN + 63) / 64;     // 782
    const int NB_O = (NN + 127) / 128;   // 391
    const int NB_S = SLEN / 256;         // 196

    // bucketed CSR build (zero global atomics)
    k_cnt<<<NBLK, 256, 0, stream>>>(src, dst, cntD, cntS);
    gscanA<<<NB_S, 256, 0, stream>>>(cntD, sincl, bsum, SLEN);
    gscanB<<<1, 256, 0, stream>>>(bsum, NB_S);
    gscanC<<<NB_S, 256, 0, stream>>>(sincl, cntD, bsum, offD, SLEN);
    gscanA<<<NB_S, 256, 0, stream>>>(cntS, sincl, bsum, SLEN);
    gscanB<<<1, 256, 0, stream>>>(bsum, NB_S);
    gscanC<<<NB_S, 256, 0, stream>>>(sincl, cntS, bsum, offS, SLEN);
    k_scat<<<NBLK, 256, 0, stream>>>(src, dst, offD, offS, edst, esrc);
    k_bcsr<<<NBUK, 256, 0, stream>>>(edst, offD, ndst, row_start, epk);
    k_bns<<<NBUK, 256, 0, stream>>>(esrc, offS, nsrc);

    k_wprep<<<(NL * HID * HID + 255) / 256, 256, 0, stream>>>(W1, W2, w1p, w2p);
    k_wfrag<<<(INF * HID + 255) / 256, 256, 0, stream>>>(Win, wfrag);
    k_gemm0<<<2 * NB_W, 256, 0, stream>>>(feat, wfrag, hbuf, part1);
    k_gfin<<<(NN * 16 + 255) / 256, 256, 0, stream>>>(hbuf, part1, bin, nsrc, hsA, f0b);

    // ping-pong bf16 hs buffers (gathers read arbitrary rows; in-place would race)
    for (int l = 0; l < NL; ++l) {
        const unsigned int* hin = (l & 1) ? hsB : hsA;
        unsigned int* hout = (l & 1) ? hsA : hsB;
        k_layer<<<NB_W, 512, 0, stream>>>(hin, epk, row_start, ndst, f0b,
                                          w1p + l * HID * HID, w2p + l * HID * HID,
                                          bvec + l * HID, nsrc, hbuf, hout, (l == NL - 1) ? 1 : 0);
    }
    k_out<<<NB_O, 256, 0, stream>>>(hbuf, Wout, bout, out);
}

// Round 7
// 1200.692 us; speedup vs baseline: 4.8751x; 1.0621x over previous
//
#include <hip/hip_runtime.h>
#include <math.h>

#define NN 50000
#define NE 800000
#define INF 512
#define HID 64
#define OUTF 40
#define NL 16
#define PADN 65

// bucketed CSR build parameters
#define NBLK 256      // edge-blocks; NE = NBLK * EPB exactly
#define EPB 3125
#define NBUK 196      // node buckets of 256 (node >> 8); 196*256 = 50176 >= NN
#define SLEN (NBUK * NBLK)  // 50176 count/offset entries

using short8 = __attribute__((ext_vector_type(8))) short;
using f32x4v = __attribute__((ext_vector_type(4))) float;

// bf16 helpers: RNE pack, cheap unpack
__device__ __forceinline__ unsigned int f2bf(float f) {
    unsigned int u = __float_as_uint(f);
    return (u + 0x7fffu + ((u >> 16) & 1u)) >> 16;
}
__device__ __forceinline__ float bflo(unsigned int w) { return __uint_as_float(w << 16); }
__device__ __forceinline__ float bfhi(unsigned int w) { return __uint_as_float(w & 0xffff0000u); }

// ---------------- bucketed CSR build (no global atomics) ----------------

__global__ __launch_bounds__(256) void k_cnt(const int* __restrict__ src, const int* __restrict__ dst,
                                             int* __restrict__ cntD, int* __restrict__ cntS) {
    __shared__ int hD[NBUK];
    __shared__ int hS[NBUK];
    int t = threadIdx.x;
    int blk = blockIdx.x;
    if (t < NBUK) { hD[t] = 0; hS[t] = 0; }
    __syncthreads();
    int s0 = blk * EPB;
    for (int i = t; i < EPB; i += 256) {
        int e = s0 + i;
        atomicAdd(&hD[dst[e] >> 8], 1);
        atomicAdd(&hS[src[e] >> 8], 1);
    }
    __syncthreads();
    if (t < NBUK) {
        cntD[t * NBLK + blk] = hD[t];
        cntS[t * NBLK + blk] = hS[t];
    }
}

__global__ __launch_bounds__(256) void gscanA(const int* __restrict__ in, int* __restrict__ incl,
                                              int* __restrict__ bsum, int len) {
    __shared__ int lds[256];
    int i = blockIdx.x * 256 + threadIdx.x;
    int v = (i < len) ? in[i] : 0;
    lds[threadIdx.x] = v;
    __syncthreads();
    for (int off = 1; off < 256; off <<= 1) {
        int t = (threadIdx.x >= off) ? lds[threadIdx.x - off] : 0;
        __syncthreads();
        lds[threadIdx.x] += t;
        __syncthreads();
    }
    if (i < len) incl[i] = lds[threadIdx.x];
    if (threadIdx.x == 255) bsum[blockIdx.x] = lds[255];
}

__global__ __launch_bounds__(256) void gscanB(int* __restrict__ bsum, int nb) {
    __shared__ int lds[256];
    int v = (threadIdx.x < nb) ? bsum[threadIdx.x] : 0;
    lds[threadIdx.x] = v;
    __syncthreads();
    for (int off = 1; off < 256; off <<= 1) {
        int t = (threadIdx.x >= off) ? lds[threadIdx.x - off] : 0;
        __syncthreads();
        lds[threadIdx.x] += t;
        __syncthreads();
    }
    if (threadIdx.x < nb) bsum[threadIdx.x] = lds[threadIdx.x] - v;  // exclusive
}

__global__ __launch_bounds__(256) void gscanC(const int* __restrict__ incl, const int* __restrict__ in,
                                              const int* __restrict__ bsum, int* __restrict__ off, int len) {
    int i = blockIdx.x * 256 + threadIdx.x;
    if (i < len) off[i] = incl[i] - in[i] + bsum[i >> 8];
}

__global__ __launch_bounds__(256) void k_scat(const int* __restrict__ src, const int* __restrict__ dst,
                                              const int* __restrict__ offD, const int* __restrict__ offS,
                                              uint2* __restrict__ edst, int* __restrict__ esrc) {
    __shared__ int cD[NBUK];
    __shared__ int cS[NBUK];
    int t = threadIdx.x;
    int blk = blockIdx.x;
    if (t < NBUK) { cD[t] = 0; cS[t] = 0; }
    __syncthreads();
    int s0 = blk * EPB;
    for (int i = t; i < EPB; i += 256) {
        int e = s0 + i;
        int d = dst[e];
        int s = src[e];
        int bD = d >> 8;
        int r = atomicAdd(&cD[bD], 1);
        uint2 v;
        v.x = (unsigned)d;
        v.y = (unsigned)s;
        edst[offD[bD * NBLK + blk] + r] = v;
        int bS = s >> 8;
        int r2 = atomicAdd(&cS[bS], 1);
        esrc[offS[bS * NBLK + blk] + r2] = s;
    }
}

// one block per dst-bucket: nd, row_start, epack — all LDS-local.
// epack[p] = (src << 6) | (dst & 63): edge list in CSR order with local dst id.
__global__ __launch_bounds__(256) void k_bcsr(const uint2* __restrict__ edst, const int* __restrict__ offD,
                                              float* __restrict__ nd, int* __restrict__ row_start,
                                              int* __restrict__ epk) {
    __shared__ int cnt[256];
    __shared__ int ex[256];
    __shared__ int cur[256];
    int b = blockIdx.x;
    int t = threadIdx.x;
    int base = offD[b * NBLK];
    int end = (b < NBUK - 1) ? offD[(b + 1) * NBLK] : NE;
    cnt[t] = 0;
    __syncthreads();
    for (int p = base + t; p < end; p += 256) {
        uint2 ed = edst[p];
        atomicAdd(&cnt[ed.x & 255], 1);
    }
    __syncthreads();
    int v = cnt[t];
    ex[t] = v;
    __syncthreads();
    for (int off = 1; off < 256; off <<= 1) {
        int tv = (t >= off) ? ex[t - off] : 0;
        __syncthreads();
        ex[t] += tv;
        __syncthreads();
    }
    int excl = ex[t] - v;
    cur[t] = excl;
    int node = b * 256 + t;
    if (node < NN) {
        nd[node] = 1.0f / sqrtf((float)max(v, 1));
        row_start[node] = base + excl;
    }
    __syncthreads();
    for (int p = base + t; p < end; p += 256) {
        uint2 ed = edst[p];
        int r = atomicAdd(&cur[ed.x & 255], 1);
        epk[base + r] = (int)((ed.y << 6) | (ed.x & 63));
    }
}

__global__ __launch_bounds__(256) void k_bns(const int* __restrict__ esrc, const int* __restrict__ offS,
                                             float* __restrict__ ns) {
    __shared__ int cnt[256];
    int b = blockIdx.x;
    int t = threadIdx.x;
    int base = offS[b * NBLK];
    int end = (b < NBUK - 1) ? offS[(b + 1) * NBLK] : NE;
    cnt[t] = 0;
    __syncthreads();
    for (int p = base + t; p < end; p += 256) {
        atomicAdd(&cnt[esrc[p] & 255], 1);
    }
    __syncthreads();
    int node = b * 256 + t;
    if (node < NN) ns[node] = 1.0f / sqrtf((float)max(cnt[t], 1));
}

// ---------------- weight prep ----------------

__global__ __launch_bounds__(256) void k_wprep(const float* __restrict__ W1, const float* __restrict__ W2,
                                               float* __restrict__ w1p, float* __restrict__ w2p) {
    int i = blockIdx.x * 256 + threadIdx.x;
    if (i < NL * HID * HID) {
        int l = i >> 12;
        int rc = i & 4095;
        int r = rc >> 6;
        int c = rc & 63;
        float beta = logf(0.5f / (float)(l + 1) + 1.0f);
        float d = (r == c) ? (1.0f - beta) : 0.0f;
        w1p[i] = beta * W1[i] + d;
        w2p[i] = beta * W2[i] + d;
    }
}

// Win (512x64 fp32, k-major) -> fragment-ordered bf16 for mfma_f32_16x16x32_bf16 B operand.
__global__ __launch_bounds__(256) void k_wfrag(const float* __restrict__ Win, unsigned short* __restrict__ wf) {
    int o = blockIdx.x * 256 + threadIdx.x;
    if (o < 16 * 4 * 64 * 8) {
        int jj = o & 7;
        int l = (o >> 3) & 63;
        int c = (o >> 9) & 3;
        int s = o >> 11;
        int colg = c * 16 + (l & 15);
        int k = s * 32 + ((l >> 4) << 3) + jj;
        wf[o] = (unsigned short)f2bf(Win[k * HID + colg]);
    }
}

// ---------------- h0 GEMM: bf16 MFMA (16x16x32), fragment-ordered LDS, K-split x2 ----------------
__global__ __launch_bounds__(256) void k_gemm0(const float* __restrict__ feat, const unsigned short* __restrict__ wf,
                                               float* __restrict__ p0, float* __restrict__ p1) {
    __shared__ unsigned int fS[2048];  // 8 KB: [s(2)][w(4)][lane(64)][4 uints = 8 bf16]
    int tid = threadIdx.x;
    int lane = tid & 63;
    int wv = tid >> 6;
    int bx = blockIdx.x;
    int w = bx >> 1;
    int kh = bx & 1;
    int nb = w * 64;
    f32x4v acc[4];
#pragma unroll
    for (int c = 0; c < 4; c++) acc[c] = {0.0f, 0.0f, 0.0f, 0.0f};

    int k0 = kh * 256;
    for (int kc = k0; kc < k0 + 256; kc += 64) {
        if (kc != k0) __syncthreads();
        float4 t[4];
#pragma unroll
        for (int j = 0; j < 4; j++) {
            int i = tid + j * 256;
            int nl = i >> 4;
            int k4 = i & 15;
            int n = min(nb + nl, NN - 1);
            t[j] = *(const float4*)(feat + (size_t)n * INF + kc + k4 * 4);
        }
#pragma unroll
        for (int j = 0; j < 4; j++) {
            int i = tid + j * 256;
            int nl = i >> 4;
            int kl = (i & 15) * 4;
            int s = kl >> 5;
            int kk = kl & 31;
            int lslot = (nl & 15) | ((kk >> 3) << 4);
            int dstu = (((s * 4 + (nl >> 4)) * 64 + lslot) << 2) + ((kk & 4) >> 1);
            fS[dstu] = f2bf(t[j].x) | (f2bf(t[j].y) << 16);
            fS[dstu + 1] = f2bf(t[j].z) | (f2bf(t[j].w) << 16);
        }
        __syncthreads();
#pragma unroll
        for (int s = 0; s < 2; ++s) {
            int sg = (kc + s * 32) >> 5;
            short8 af = *(const short8*)&fS[((s * 4 + wv) * 64 + lane) << 2];
            short8 bf[4];
#pragma unroll
            for (int c = 0; c < 4; ++c)
                bf[c] = *(const short8*)(wf + ((size_t)(sg * 4 + c) * 64 + lane) * 8);
#pragma unroll
            for (int c = 0; c < 4; ++c)
                acc[c] = __builtin_amdgcn_mfma_f32_16x16x32_bf16(af, bf[c], acc[c], 0, 0, 0);
        }
    }
    float* p = kh ? p1 : p0;
    int nodeb = nb + (wv << 4) + ((lane >> 4) << 2);
    int colb = lane & 15;
#pragma unroll
    for (int r = 0; r < 4; ++r) {
        int node = nodeb + r;
        if (node < NN) {
            float* pp = p + (size_t)node * HID + colb;
#pragma unroll
            for (int c = 0; c < 4; ++c) pp[c * 16] = acc[c][r];
        }
    }
}

// combine: p0+p1, +bias, relu, ns-scale, bf16 pack -> hs, f0b
__global__ __launch_bounds__(256) void k_gfin(const float* __restrict__ p0, const float* __restrict__ p1,
                                              const float* __restrict__ bin, const float* __restrict__ ns,
                                              unsigned int* __restrict__ hs, unsigned int* __restrict__ f0b) {
    int i = blockIdx.x * 256 + threadIdx.x;
    if (i >= NN * 16) return;
    int node = i >> 4;
    int q = i & 15;
    float4 a = ((const float4*)p0)[i];
    float4 b = ((const float4*)p1)[i];
    float4 bi = ((const float4*)bin)[q];
    float nsv = ns[node];
    float q0 = fmaxf(a.x + b.x + bi.x, 0.0f);
    float q1 = fmaxf(a.y + b.y + bi.y, 0.0f);
    float q2 = fmaxf(a.z + b.z + bi.z, 0.0f);
    float q3 = fmaxf(a.w + b.w + bi.w, 0.0f);
    uint2 pk;
    pk.x = f2bf(q0 * nsv) | (f2bf(q1 * nsv) << 16);
    pk.y = f2bf(q2 * nsv) | (f2bf(q3 * nsv) << 16);
    *(uint2*)(hs + (size_t)node * 32 + q * 2) = pk;
    uint2 pf;
    pf.x = f2bf(q0 * 0.1f) | (f2bf(q1 * 0.1f) << 16);
    pf.y = f2bf(q2 * 0.1f) | (f2bf(q3 * 0.1f) << 16);
    *(uint2*)(f0b + (size_t)node * 32 + q * 2) = pf;
}

// ---------------- fused layer: slot-run aggregation, 4-deep chunked pipeline ----------------
// 512 threads = 8 waves. Block owns 64 dst-nodes; CSR edges contiguous [base,end).
// 64 slots x 8 lanes; slot owns a contiguous ~len-edge slice (dst-sorted -> ~2 distinct nodes).
// Chunked x4: prefetch next chunk's epk while current chunk's 4 independent uint4 row-loads are
// in flight (8 loads deep/thread vs 1 in R6's serial loop). Register accumulate; atomic flush
// only at dst-change (slices decorrelated -> no same-address contention).
__global__ __launch_bounds__(512) void k_layer(const unsigned int* __restrict__ hs_in, const int* __restrict__ epk,
                                               const int* __restrict__ row_start,
                                               const float* __restrict__ nd, const unsigned int* __restrict__ f0b,
                                               const float* __restrict__ w1p, const float* __restrict__ w2p,
                                               const float* __restrict__ bias, const float* __restrict__ ns,
                                               float* __restrict__ h, unsigned int* __restrict__ hs_out, int write_h) {
    __shared__ float fT[HID * PADN];
    __shared__ float f0T[HID * PADN];
    __shared__ float ndS[64];
    int tid = threadIdx.x;
    int lane = tid & 63;
    int wv = tid >> 6;   // 0..7
    int nb = blockIdx.x * 64;

    // zero accumulator tile
    for (int i = tid; i < HID * PADN; i += 512) fT[i] = 0.0f;
    // stage f0 (bf16) -> LDS transposed fp32
    for (int i = tid; i < 64 * 16; i += 512) {
        int nl = i >> 4;
        int q = i & 15;
        int n = min(nb + nl, NN - 1);
        uint2 v = *(const uint2*)(f0b + (size_t)n * 32 + q * 2);
        f0T[(q * 4 + 0) * PADN + nl] = bflo(v.x);
        f0T[(q * 4 + 1) * PADN + nl] = bfhi(v.x);
        f0T[(q * 4 + 2) * PADN + nl] = bflo(v.y);
        f0T[(q * 4 + 3) * PADN + nl] = bfhi(v.y);
    }
    if (tid < 64) ndS[tid] = nd[min(nb + tid, NN - 1)];
    int base = row_start[nb];
    int end = (nb + 64 < NN) ? row_start[nb + 64] : NE;
    __syncthreads();

    // slot-run aggregation, 4-edge chunks, epk prefetched one chunk ahead
    {
        int slot = tid >> 3;   // 0..63
        int j = tid & 7;       // lane-in-slot: owns dims [8j, 8j+8)
        int d0 = j * 8;
        int E = end - base;
        int len = (E + 63) >> 6;
        int e0 = base + slot * len;
        int e1 = min(e0 + len, end);
        float a0 = 0.f, a1 = 0.f, a2 = 0.f, a3 = 0.f, a4 = 0.f, a5 = 0.f, a6 = 0.f, a7 = 0.f;
        int cur = -1;
        int e = e0;
        int rem = (e1 > e0) ? (e1 - e0) : 0;
        unsigned int up0 = 0, up1 = 0, up2 = 0, up3 = 0;
        {
            int n = min(rem, 4);
            if (n > 0) up0 = (unsigned)epk[e + 0];
            if (n > 1) up1 = (unsigned)epk[e + 1];
            if (n > 2) up2 = (unsigned)epk[e + 2];
            if (n > 3) up3 = (unsigned)epk[e + 3];
        }
        while (rem > 0) {
            int n = min(rem, 4);
            int nn = min(rem - n, 4);
            // prefetch next chunk's epk (in flight across this chunk's work)
            unsigned int un0 = 0, un1 = 0, un2 = 0, un3 = 0;
            if (nn > 0) un0 = (unsigned)epk[e + n + 0];
            if (nn > 1) un1 = (unsigned)epk[e + n + 1];
            if (nn > 2) un2 = (unsigned)epk[e + n + 2];
            if (nn > 3) un3 = (unsigned)epk[e + n + 3];
            // issue 4 independent row loads
            uint4 v0 = {0, 0, 0, 0}, v1 = {0, 0, 0, 0}, v2 = {0, 0, 0, 0}, v3 = {0, 0, 0, 0};
            if (n > 0) v0 = *(const uint4*)(hs_in + (size_t)(up0 >> 6) * 32 + j * 4);
            if (n > 1) v1 = *(const uint4*)(hs_in + (size_t)(up1 >> 6) * 32 + j * 4);
            if (n > 2) v2 = *(const uint4*)(hs_in + (size_t)(up2 >> 6) * 32 + j * 4);
            if (n > 3) v3 = *(const uint4*)(hs_in + (size_t)(up3 >> 6) * 32 + j * 4);
            // accumulate with flush-at-dst-change
#define ACC_EDGE(U, V)                                                      \
            {                                                               \
                int dl = (int)((U) & 63u);                                  \
                if (dl != cur) {                                            \
                    if (cur >= 0) {                                         \
                        float* fd = fT + d0 * PADN + cur;                   \
                        atomicAdd(fd + 0 * PADN, a0);                       \
                        atomicAdd(fd + 1 * PADN, a1);                       \
                        atomicAdd(fd + 2 * PADN, a2);                       \
                        atomicAdd(fd + 3 * PADN, a3);                       \
                        atomicAdd(fd + 4 * PADN, a4);                       \
                        atomicAdd(fd + 5 * PADN, a5);                       \
                        atomicAdd(fd + 6 * PADN, a6);                       \
                        atomicAdd(fd + 7 * PADN, a7);                       \
                    }                                                       \
                    a0 = a1 = a2 = a3 = a4 = a5 = a6 = a7 = 0.f;            \
                    cur = dl;                                               \
                }                                                           \
                a0 += bflo((V).x);                                          \
                a1 += bfhi((V).x);                                          \
                a2 += bflo((V).y);                                          \
                a3 += bfhi((V).y);                                          \
                a4 += bflo((V).z);                                          \
                a5 += bfhi((V).z);                                          \
                a6 += bflo((V).w);                                          \
                a7 += bfhi((V).w);                                          \
            }
            if (n > 0) ACC_EDGE(up0, v0);
            if (n > 1) ACC_EDGE(up1, v1);
            if (n > 2) ACC_EDGE(up2, v2);
            if (n > 3) ACC_EDGE(up3, v3);
#undef ACC_EDGE
            up0 = un0; up1 = un1; up2 = un2; up3 = un3;
            e += n;
            rem -= n;
        }
        if (cur >= 0) {
            float* fd = fT + d0 * PADN + cur;
            atomicAdd(fd + 0 * PADN, a0);
            atomicAdd(fd + 1 * PADN, a1);
            atomicAdd(fd + 2 * PADN, a2);
            atomicAdd(fd + 3 * PADN, a3);
            atomicAdd(fd + 4 * PADN, a4);
            atomicAdd(fd + 5 * PADN, a5);
            atomicAdd(fd + 6 * PADN, a6);
            atomicAdd(fd + 7 * PADN, a7);
        }
    }
    __syncthreads();

    // scale by 0.9 * nd[dst]  (consecutive tids -> consecutive LDS addrs, conflict-free)
    for (int i = tid; i < HID * 64; i += 512) {
        int d = i >> 6;
        int nl = i & 63;
        fT[d * PADN + nl] *= 0.9f * ndS[nl];
    }
    __syncthreads();

    // matmul: lane = node, wave = 8-col group; weights wave-uniform -> scalar loads
    int cg = __builtin_amdgcn_readfirstlane(wv) * 8;
    const float* w1b = w1p + cg;
    const float* w2b = w2p + cg;
    float acc[8];
#pragma unroll
    for (int c = 0; c < 8; c++) acc[c] = 0.0f;
    for (int k = 0; k < HID; ++k) {
        float fk = fT[k * PADN + lane];
        float f0k = f0T[k * PADN + lane];
        const float* w1r = w1b + (size_t)k * HID;
        const float* w2r = w2b + (size_t)k * HID;
#pragma unroll
        for (int c = 0; c < 8; c++) acc[c] += fk * w1r[c] + f0k * w2r[c];
    }
    int node = nb + lane;
    if (node < NN) {
        float nsv = ns[node];
        const float* bp = bias + cg;
        float q[8];
#pragma unroll
        for (int c = 0; c < 8; c++) q[c] = fmaxf(acc[c] + bp[c], 0.0f);
        uint2* hsp = (uint2*)(hs_out + (size_t)node * 32 + cg / 2);
#pragma unroll
        for (int c4 = 0; c4 < 2; c4++) {
            uint2 pk;
            pk.x = f2bf(q[c4 * 4 + 0] * nsv) | (f2bf(q[c4 * 4 + 1] * nsv) << 16);
            pk.y = f2bf(q[c4 * 4 + 2] * nsv) | (f2bf(q[c4 * 4 + 3] * nsv) << 16);
            hsp[c4] = pk;
        }
        if (write_h) {
            float4* hp = (float4*)(h + (size_t)node * HID + cg);
            float4 v0 = {q[0], q[1], q[2], q[3]};
            float4 v1 = {q[4], q[5], q[6], q[7]};
            hp[0] = v0;
            hp[1] = v1;
        }
    }
}

// ---------------- output: block = 128 nodes; wave pair splits the 40 cols; LDS lse reduce ----------------
__global__ __launch_bounds__(256) void k_out(const float* __restrict__ h, const float* __restrict__ Wout,
                                             const float* __restrict__ bout, float* __restrict__ out) {
    __shared__ float red_mx[4][64];
    __shared__ float red_s[4][64];
    int tid = threadIdx.x;
    int lane = tid & 63;
    int wv = tid >> 6;
    int half = wv & 1;
    int grp = wv >> 1;
    int node = blockIdx.x * 128 + grp * 64 + lane;
    int nodec = min(node, NN - 1);
    float acc[20];
#pragma unroll
    for (int c = 0; c < 20; c++) acc[c] = 0.0f;
    const float4* hr = (const float4*)(h + (size_t)nodec * HID);
    const float* wb = Wout + half * 20;
    for (int kk = 0; kk < HID / 4; ++kk) {
        float4 a = hr[kk];
        float av[4] = {a.x, a.y, a.z, a.w};
#pragma unroll
        for (int j = 0; j < 4; j++) {
            const float* wr = wb + (size_t)(kk * 4 + j) * OUTF;
#pragma unroll
            for (int c = 0; c < 20; c++) acc[c] += av[j] * wr[c];
        }
    }
    const float* bp = bout + half * 20;
#pragma unroll
    for (int c = 0; c < 20; c++) acc[c] += bp[c];
    float mx = acc[0];
#pragma unroll
    for (int c = 1; c < 20; c++) mx = fmaxf(mx, acc[c]);
    red_mx[wv][lane] = mx;
    __syncthreads();
    float gmx = fmaxf(mx, red_mx[wv ^ 1][lane]);
    float s = 0.0f;
#pragma unroll
    for (int c = 0; c < 20; c++) s += expf(acc[c] - gmx);
    red_s[wv][lane] = s;
    __syncthreads();
    float lse = logf(s + red_s[wv ^ 1][lane]) + gmx;
    if (node < NN) {
        float4* op = (float4*)(out + (size_t)node * OUTF + half * 20);
#pragma unroll
        for (int q = 0; q < 5; q++) {
            float4 v;
            v.x = acc[q * 4 + 0] - lse;
            v.y = acc[q * 4 + 1] - lse;
            v.z = acc[q * 4 + 2] - lse;
            v.w = acc[q * 4 + 3] - lse;
            op[q] = v;
        }
    }
}

extern "C" void kernel_launch(void* const* d_in, const int* in_sizes, int n_in,
                              void* d_out, int out_size, void* d_ws, size_t ws_size,
                              hipStream_t stream) {
    const float* feat = (const float*)d_in[0];
    const float* Win  = (const float*)d_in[1];
    const float* bin  = (const float*)d_in[2];
    const float* W1   = (const float*)d_in[3];
    const float* W2   = (const float*)d_in[4];
    const float* bvec = (const float*)d_in[5];
    const float* Wout = (const float*)d_in[6];
    const float* bout = (const float*)d_in[7];
    const int*   src  = (const int*)d_in[8];
    const int*   dst  = (const int*)d_in[9];
    float* out = (float*)d_out;

    char* ws = (char*)d_ws;
    size_t off = 0;
    auto take = [&](size_t bytes) {
        void* p = ws + off;
        off += (bytes + 255) & ~(size_t)255;
        return p;
    };
    int* bsum      = (int*)take(256 * 4);
    int* row_start = (int*)take(NN * 4);
    int* epk       = (int*)take(NE * 4);
    float* nsrc    = (float*)take(NN * 4);
    float* ndst    = (float*)take(NN * 4);
    int* cntD      = (int*)take(SLEN * 4);
    int* cntS      = (int*)take(SLEN * 4);
    int* offD      = (int*)take(SLEN * 4);
    int* offS      = (int*)take(SLEN * 4);
    int* sincl     = (int*)take(SLEN * 4);
    float* w1p     = (float*)take((size_t)NL * HID * HID * 4);
    float* w2p     = (float*)take((size_t)NL * HID * HID * 4);
    unsigned short* wfrag = (unsigned short*)take((size_t)INF * HID * 2);
    unsigned int* f0b = (unsigned int*)take((size_t)NN * HID * 2);  // bf16
    float* hbuf    = (float*)take((size_t)NN * HID * 4);            // gemm0 partial p0; edst alias
    float* part1   = (float*)take((size_t)NN * HID * 4);            // gemm0 partial p1; esrc alias
    unsigned int* hsA = (unsigned int*)take((size_t)NN * HID * 2);  // bf16
    unsigned int* hsB = (unsigned int*)take((size_t)NN * HID * 2);  // bf16

    // setup-phase aliases (dead before k_gemm0 writes them)
    uint2* edst = (uint2*)hbuf;   // NE * 8B = 6.4 MB <= 12.8 MB
    int* esrc   = (int*)part1;    // NE * 4B = 3.2 MB

    const int NB_W = (NN + 63) / 64;     // 782
    const int NB_O = (NN + 127) / 128;   // 391
    const int NB_S = SLEN / 256;         // 196

    // bucketed CSR build (zero global atomics)
    k_cnt<<<NBLK, 256, 0, stream>>>(src, dst, cntD, cntS);
    gscanA<<<NB_S, 256, 0, stream>>>(cntD, sincl, bsum, SLEN);
    gscanB<<<1, 256, 0, stream>>>(bsum, NB_S);
    gscanC<<<NB_S, 256, 0, stream>>>(sincl, cntD, bsum, offD, SLEN);
    gscanA<<<NB_S, 256, 0, stream>>>(cntS, sincl, bsum, SLEN);
    gscanB<<<1, 256, 0, stream>>>(bsum, NB_S);
    gscanC<<<NB_S, 256, 0, stream>>>(sincl, cntS, bsum, offS, SLEN);
    k_scat<<<NBLK, 256, 0, stream>>>(src, dst, offD, offS, edst, esrc);
    k_bcsr<<<NBUK, 256, 0, stream>>>(edst, offD, ndst, row_start, epk);
    k_bns<<<NBUK, 256, 0, stream>>>(esrc, offS, nsrc);

    k_wprep<<<(NL * HID * HID + 255) / 256, 256, 0, stream>>>(W1, W2, w1p, w2p);
    k_wfrag<<<(INF * HID + 255) / 256, 256, 0, stream>>>(Win, wfrag);
    k_gemm0<<<2 * NB_W, 256, 0, stream>>>(feat, wfrag, hbuf, part1);
    k_gfin<<<(NN * 16 + 255) / 256, 256, 0, stream>>>(hbuf, part1, bin, nsrc, hsA, f0b);

    // ping-pong bf16 hs buffers (gathers read arbitrary rows; in-place would race)
    for (int l = 0; l < NL; ++l) {
        const unsigned int* hin = (l & 1) ? hsB : hsA;
        unsigned int* hout = (l & 1) ? hsA : hsB;
        k_layer<<<NB_W, 512, 0, stream>>>(hin, epk, row_start, ndst, f0b,
                                          w1p + l * HID * HID, w2p + l * HID * HID,
                                          bvec + l * HID, nsrc, hbuf, hout, (l == NL - 1) ? 1 : 0);
    }
    k_out<<<NB_O, 256, 0, stream>>>(hbuf, Wout, bout, out);
}

// Round 8
// 578.851 us; speedup vs baseline: 10.1123x; 2.0743x over previous
//
#include <hip/hip_runtime.h>
#include <math.h>

#define NN 50000
#define NE 800000
#define INF 512
#define HID 64
#define OUTF 40
#define NL 16

// bucketed CSR build parameters
#define NBLK 256      // edge-blocks; NE = NBLK * EPB exactly
#define EPB 3125
#define NBUK 196      // node buckets of 256 (node >> 8); 196*256 = 50176 >= NN
#define SLEN (NBUK * NBLK)  // 50176 count/offset entries

// layer tile
#define TN 32         // nodes per k_layer block
#define FP 72         // LDS row pitch in bf16 (144 B, 16B-aligned)

using short8 = __attribute__((ext_vector_type(8))) short;
using f32x4v = __attribute__((ext_vector_type(4))) float;

// bf16 helpers: RNE pack, cheap unpack
__device__ __forceinline__ unsigned int f2bf(float f) {
    unsigned int u = __float_as_uint(f);
    return (u + 0x7fffu + ((u >> 16) & 1u)) >> 16;
}
__device__ __forceinline__ float bflo(unsigned int w) { return __uint_as_float(w << 16); }
__device__ __forceinline__ float bfhi(unsigned int w) { return __uint_as_float(w & 0xffff0000u); }
__device__ __forceinline__ float bfs(unsigned short u) { return __uint_as_float(((unsigned)u) << 16); }

// ---------------- bucketed CSR build (no global atomics) ----------------

__global__ __launch_bounds__(256) void k_cnt(const int* __restrict__ src, const int* __restrict__ dst,
                                             int* __restrict__ cntD, int* __restrict__ cntS) {
    __shared__ int hD[NBUK];
    __shared__ int hS[NBUK];
    int t = threadIdx.x;
    int blk = blockIdx.x;
    if (t < NBUK) { hD[t] = 0; hS[t] = 0; }
    __syncthreads();
    int s0 = blk * EPB;
    for (int i = t; i < EPB; i += 256) {
        int e = s0 + i;
        atomicAdd(&hD[dst[e] >> 8], 1);
        atomicAdd(&hS[src[e] >> 8], 1);
    }
    __syncthreads();
    if (t < NBUK) {
        cntD[t * NBLK + blk] = hD[t];
        cntS[t * NBLK + blk] = hS[t];
    }
}

__global__ __launch_bounds__(256) void gscanA(const int* __restrict__ in, int* __restrict__ incl,
                                              int* __restrict__ bsum, int len) {
    __shared__ int lds[256];
    int i = blockIdx.x * 256 + threadIdx.x;
    int v = (i < len) ? in[i] : 0;
    lds[threadIdx.x] = v;
    __syncthreads();
    for (int off = 1; off < 256; off <<= 1) {
        int t = (threadIdx.x >= off) ? lds[threadIdx.x - off] : 0;
        __syncthreads();
        lds[threadIdx.x] += t;
        __syncthreads();
    }
    if (i < len) incl[i] = lds[threadIdx.x];
    if (threadIdx.x == 255) bsum[blockIdx.x] = lds[255];
}

__global__ __launch_bounds__(256) void gscanB(int* __restrict__ bsum, int nb) {
    __shared__ int lds[256];
    int v = (threadIdx.x < nb) ? bsum[threadIdx.x] : 0;
    lds[threadIdx.x] = v;
    __syncthreads();
    for (int off = 1; off < 256; off <<= 1) {
        int t = (threadIdx.x >= off) ? lds[threadIdx.x - off] : 0;
        __syncthreads();
        lds[threadIdx.x] += t;
        __syncthreads();
    }
    if (threadIdx.x < nb) bsum[threadIdx.x] = lds[threadIdx.x] - v;  // exclusive
}

__global__ __launch_bounds__(256) void gscanC(const int* __restrict__ incl, const int* __restrict__ in,
                                              const int* __restrict__ bsum, int* __restrict__ off, int len) {
    int i = blockIdx.x * 256 + threadIdx.x;
    if (i < len) off[i] = incl[i] - in[i] + bsum[i >> 8];
}

__global__ __launch_bounds__(256) void k_scat(const int* __restrict__ src, const int* __restrict__ dst,
                                              const int* __restrict__ offD, const int* __restrict__ offS,
                                              uint2* __restrict__ edst, int* __restrict__ esrc) {
    __shared__ int cD[NBUK];
    __shared__ int cS[NBUK];
    int t = threadIdx.x;
    int blk = blockIdx.x;
    if (t < NBUK) { cD[t] = 0; cS[t] = 0; }
    __syncthreads();
    int s0 = blk * EPB;
    for (int i = t; i < EPB; i += 256) {
        int e = s0 + i;
        int d = dst[e];
        int s = src[e];
        int bD = d >> 8;
        int r = atomicAdd(&cD[bD], 1);
        uint2 v;
        v.x = (unsigned)d;
        v.y = (unsigned)s;
        edst[offD[bD * NBLK + blk] + r] = v;
        int bS = s >> 8;
        int r2 = atomicAdd(&cS[bS], 1);
        esrc[offS[bS * NBLK + blk] + r2] = s;
    }
}

// one block per dst-bucket: nd, row_start, col (CSR src list) — all LDS-local
__global__ __launch_bounds__(256) void k_bcsr(const uint2* __restrict__ edst, const int* __restrict__ offD,
                                              float* __restrict__ nd, int* __restrict__ row_start,
                                              int* __restrict__ col) {
    __shared__ int cnt[256];
    __shared__ int ex[256];
    __shared__ int cur[256];
    int b = blockIdx.x;
    int t = threadIdx.x;
    int base = offD[b * NBLK];
    int end = (b < NBUK - 1) ? offD[(b + 1) * NBLK] : NE;
    cnt[t] = 0;
    __syncthreads();
    for (int p = base + t; p < end; p += 256) {
        uint2 ed = edst[p];
        atomicAdd(&cnt[ed.x & 255], 1);
    }
    __syncthreads();
    int v = cnt[t];
    ex[t] = v;
    __syncthreads();
    for (int off = 1; off < 256; off <<= 1) {
        int tv = (t >= off) ? ex[t - off] : 0;
        __syncthreads();
        ex[t] += tv;
        __syncthreads();
    }
    int excl = ex[t] - v;
    cur[t] = excl;
    int node = b * 256 + t;
    if (node < NN) {
        nd[node] = 1.0f / sqrtf((float)max(v, 1));
        row_start[node] = base + excl;
    }
    __syncthreads();
    for (int p = base + t; p < end; p += 256) {
        uint2 ed = edst[p];
        int r = atomicAdd(&cur[ed.x & 255], 1);
        col[base + r] = (int)ed.y;
    }
}

__global__ __launch_bounds__(256) void k_bns(const int* __restrict__ esrc, const int* __restrict__ offS,
                                             float* __restrict__ ns) {
    __shared__ int cnt[256];
    int b = blockIdx.x;
    int t = threadIdx.x;
    int base = offS[b * NBLK];
    int end = (b < NBUK - 1) ? offS[(b + 1) * NBLK] : NE;
    cnt[t] = 0;
    __syncthreads();
    for (int p = base + t; p < end; p += 256) {
        atomicAdd(&cnt[esrc[p] & 255], 1);
    }
    __syncthreads();
    int node = b * 256 + t;
    if (node < NN) ns[node] = 1.0f / sqrtf((float)max(cnt[t], 1));
}

// ---------------- weight prep ----------------

// Layer weights -> beta-scaled bf16 MFMA B-fragments. Layout [l][s(4)][c(4)][lane(64)][j(8)].
// Combined K=128: s<2 -> W1 rows k=s*32+8*(lane>>4)+j ; s>=2 -> W2 rows (s-2)*32+8*(lane>>4)+j.
// col = c*16 + (lane&15). Identity path NOT folded (added fp32 in epilogue).
__global__ __launch_bounds__(256) void k_wcat(const float* __restrict__ W1, const float* __restrict__ W2,
                                              unsigned short* __restrict__ wc) {
    int o = blockIdx.x * 256 + threadIdx.x;
    if (o >= NL * 4 * 4 * 64 * 8) return;
    int j = o & 7;
    int ln = (o >> 3) & 63;
    int c = (o >> 9) & 3;
    int s = (o >> 11) & 3;
    int l = o >> 13;
    int colg = c * 16 + (ln & 15);
    int k = (s & 1) * 32 + ((ln >> 4) << 3) + j;
    float beta = logf(0.5f / (float)(l + 1) + 1.0f);
    const float* W = (s < 2) ? W1 : W2;
    wc[o] = (unsigned short)f2bf(beta * W[((size_t)l * 64 + k) * 64 + colg]);
}

// Win (512x64 fp32, k-major) -> fragment-ordered bf16 for mfma_f32_16x16x32_bf16 B operand.
__global__ __launch_bounds__(256) void k_wfrag(const float* __restrict__ Win, unsigned short* __restrict__ wf) {
    int o = blockIdx.x * 256 + threadIdx.x;
    if (o < 16 * 4 * 64 * 8) {
        int jj = o & 7;
        int l = (o >> 3) & 63;
        int c = (o >> 9) & 3;
        int s = o >> 11;
        int colg = c * 16 + (l & 15);
        int k = s * 32 + ((l >> 4) << 3) + jj;
        wf[o] = (unsigned short)f2bf(Win[k * HID + colg]);
    }
}

// ---------------- h0 GEMM: bf16 MFMA (16x16x32), fragment-ordered LDS, K-split x2 ----------------
__global__ __launch_bounds__(256) void k_gemm0(const float* __restrict__ feat, const unsigned short* __restrict__ wf,
                                               float* __restrict__ p0, float* __restrict__ p1) {
    __shared__ unsigned int fS[2048];  // 8 KB: [s(2)][w(4)][lane(64)][4 uints = 8 bf16]
    int tid = threadIdx.x;
    int lane = tid & 63;
    int wv = tid >> 6;
    int bx = blockIdx.x;
    int w = bx >> 1;
    int kh = bx & 1;
    int nb = w * 64;
    f32x4v acc[4];
#pragma unroll
    for (int c = 0; c < 4; c++) acc[c] = {0.0f, 0.0f, 0.0f, 0.0f};

    int k0 = kh * 256;
    for (int kc = k0; kc < k0 + 256; kc += 64) {
        if (kc != k0) __syncthreads();
        float4 t[4];
#pragma unroll
        for (int j = 0; j < 4; j++) {
            int i = tid + j * 256;
            int nl = i >> 4;
            int k4 = i & 15;
            int n = min(nb + nl, NN - 1);
            t[j] = *(const float4*)(feat + (size_t)n * INF + kc + k4 * 4);
        }
#pragma unroll
        for (int j = 0; j < 4; j++) {
            int i = tid + j * 256;
            int nl = i >> 4;
            int kl = (i & 15) * 4;
            int s = kl >> 5;
            int kk = kl & 31;
            int lslot = (nl & 15) | ((kk >> 3) << 4);
            int dstu = (((s * 4 + (nl >> 4)) * 64 + lslot) << 2) + ((kk & 4) >> 1);
            fS[dstu] = f2bf(t[j].x) | (f2bf(t[j].y) << 16);
            fS[dstu + 1] = f2bf(t[j].z) | (f2bf(t[j].w) << 16);
        }
        __syncthreads();
#pragma unroll
        for (int s = 0; s < 2; ++s) {
            int sg = (kc + s * 32) >> 5;
            short8 af = *(const short8*)&fS[((s * 4 + wv) * 64 + lane) << 2];
            short8 bf[4];
#pragma unroll
            for (int c = 0; c < 4; ++c)
                bf[c] = *(const short8*)(wf + ((size_t)(sg * 4 + c) * 64 + lane) * 8);
#pragma unroll
            for (int c = 0; c < 4; ++c)
                acc[c] = __builtin_amdgcn_mfma_f32_16x16x32_bf16(af, bf[c], acc[c], 0, 0, 0);
        }
    }
    float* p = kh ? p1 : p0;
    int nodeb = nb + (wv << 4) + ((lane >> 4) << 2);
    int colb = lane & 15;
#pragma unroll
    for (int r = 0; r < 4; ++r) {
        int node = nodeb + r;
        if (node < NN) {
            float* pp = p + (size_t)node * HID + colb;
#pragma unroll
            for (int c = 0; c < 4; ++c) pp[c * 16] = acc[c][r];
        }
    }
}

// combine: p0+p1, +bias, relu, ns-scale, bf16 pack -> hs, f0b
__global__ __launch_bounds__(256) void k_gfin(const float* __restrict__ p0, const float* __restrict__ p1,
                                              const float* __restrict__ bin, const float* __restrict__ ns,
                                              unsigned int* __restrict__ hs, unsigned int* __restrict__ f0b) {
    int i = blockIdx.x * 256 + threadIdx.x;
    if (i >= NN * 16) return;
    int node = i >> 4;
    int q = i & 15;
    float4 a = ((const float4*)p0)[i];
    float4 b = ((const float4*)p1)[i];
    float4 bi = ((const float4*)bin)[q];
    float nsv = ns[node];
    float q0 = fmaxf(a.x + b.x + bi.x, 0.0f);
    float q1 = fmaxf(a.y + b.y + bi.y, 0.0f);
    float q2 = fmaxf(a.z + b.z + bi.z, 0.0f);
    float q3 = fmaxf(a.w + b.w + bi.w, 0.0f);
    uint2 pk;
    pk.x = f2bf(q0 * nsv) | (f2bf(q1 * nsv) << 16);
    pk.y = f2bf(q2 * nsv) | (f2bf(q3 * nsv) << 16);
    *(uint2*)(hs + (size_t)node * 32 + q * 2) = pk;
    uint2 pf;
    pf.x = f2bf(q0 * 0.1f) | (f2bf(q1 * 0.1f) << 16);
    pf.y = f2bf(q2 * 0.1f) | (f2bf(q3 * 0.1f) << 16);
    *(uint2*)(f0b + (size_t)node * 32 + q * 2) = pf;
}

// ---------------- fused layer: R4 grouped-gather agg + MFMA matmul, 32-node tiles ----------------
// 256 threads = 4 waves. 16-lane group per node (16 groups, 2 passes), pv[8]x2 gathers in flight,
// idx prefetch. Agg accumulates fp32 in regs -> bf16 fS[node][k] (MFMA A layout). Matmul:
// rst = beta([f|f0] @ [[W1],[W2]]) via 8 mfma/wave (K=128) + fp32 epilogue (1-beta)(f+f0)+bias.
__global__ __launch_bounds__(256) void k_layer(const unsigned int* __restrict__ hs_in, const int* __restrict__ col,
                                               const int* __restrict__ row_start,
                                               const float* __restrict__ nd, const unsigned int* __restrict__ f0b,
                                               const unsigned short* __restrict__ wc, const float* __restrict__ bias,
                                               const float* __restrict__ ns, float omb,
                                               float* __restrict__ h, unsigned int* __restrict__ hs_out, int write_h) {
    __shared__ unsigned short fS[TN * FP];   // agg f (scaled 0.9*nd), bf16
    __shared__ unsigned short f0S[TN * FP];  // f0, bf16
    __shared__ unsigned short oS[TN * FP];   // output bounce
    __shared__ float nsS[TN];
    int tid = threadIdx.x;
    int lane = tid & 63;
    int wv = tid >> 6;   // 0..3
    int nb = blockIdx.x * TN;
    int g = lane >> 4;   // group-in-wave 0..3
    int ql = lane & 15;  // lane within group: owns dims [4ql, 4ql+4)

    // stage f0 tile: thread i -> node i>>3, 16B segment i&7
    {
        int nl = tid >> 3, sg = tid & 7;
        int n = min(nb + nl, NN - 1);
        uint4 v = *(const uint4*)(f0b + (size_t)n * 32 + sg * 4);
        *(uint4*)&f0S[nl * FP + sg * 8] = v;
    }
    if (tid < TN) nsS[tid] = ns[min(nb + tid, NN - 1)];

    // hoist both passes' metadata + first-chunk col indices
    int nlP[2], baseP[2], degP[2], idxP[2];
    float ndP[2];
#pragma unroll
    for (int p = 0; p < 2; ++p) {
        int nl = p * 16 + wv * 4 + g;
        int n = min(nb + nl, NN - 1);
        nlP[p] = nl;
        int base = row_start[n];
        int nxt = (n < NN - 1) ? row_start[n + 1] : NE;
        baseP[p] = base;
        degP[p] = nxt - base;
        ndP[p] = nd[n];
    }
#pragma unroll
    for (int p = 0; p < 2; ++p) {
        idxP[p] = (ql < min(16, degP[p])) ? col[baseP[p] + ql] : 0;
    }

    // grouped-gather aggregation (R4 structure): 16 row-gathers in flight per chunk
#pragma unroll
    for (int pass = 0; pass < 2; ++pass) {
        int base = baseP[pass];
        int deg = degP[pass];
        int idxv = idxP[pass];
        float ax = 0.0f, ay = 0.0f, az = 0.0f, aw = 0.0f;
        for (int done = 0; done < deg; done += 16) {
            int cnt = min(16, deg - done);
            int nxt = done + 16;
            int idxn = 0;
            if (nxt < deg && ql < deg - nxt) idxn = col[base + nxt + ql];
            uint2 pv[8];
#pragma unroll
            for (int e = 0; e < 8; ++e) {
                int s = __shfl(idxv, (g << 4) | e, 64);
                uint2 v = {0u, 0u};
                if (e < cnt) v = *(const uint2*)(hs_in + (size_t)s * 32 + ql * 2);
                pv[e] = v;
            }
#pragma unroll
            for (int e = 0; e < 8; ++e) {
                ax += bflo(pv[e].x);
                ay += bfhi(pv[e].x);
                az += bflo(pv[e].y);
                aw += bfhi(pv[e].y);
            }
#pragma unroll
            for (int e = 0; e < 8; ++e) {
                int s = __shfl(idxv, (g << 4) | (8 + e), 64);
                uint2 v = {0u, 0u};
                if (8 + e < cnt) v = *(const uint2*)(hs_in + (size_t)s * 32 + ql * 2);
                pv[e] = v;
            }
#pragma unroll
            for (int e = 0; e < 8; ++e) {
                ax += bflo(pv[e].x);
                ay += bfhi(pv[e].x);
                az += bflo(pv[e].y);
                aw += bfhi(pv[e].y);
            }
            idxv = idxn;
        }
        float sc = 0.9f * ndP[pass];
        int nl = nlP[pass];
        // f = sc*agg -> bf16, dims 4ql..4ql+3 of row nl (8B write, aligned)
        uint2 w;
        w.x = f2bf(ax * sc) | (f2bf(ay * sc) << 16);
        w.y = f2bf(az * sc) | (f2bf(aw * sc) << 16);
        *(uint2*)&fS[nl * FP + ql * 4] = w;
    }
    __syncthreads();

    // MFMA: wave wv owns col-tile wv (cols wv*16..+15); m-tiles = node halves; K=128 = 4 steps
    int hi = lane >> 4;
    int lo = lane & 15;
    f32x4v acc0 = {0.0f, 0.0f, 0.0f, 0.0f};
    f32x4v acc1 = {0.0f, 0.0f, 0.0f, 0.0f};
#pragma unroll
    for (int s = 0; s < 4; ++s) {
        short8 bf = *(const short8*)(wc + ((size_t)(s * 4 + wv) * 64 + lane) * 8);
        const unsigned short* ab = (s < 2) ? fS : f0S;
        int ko = (s & 1) * 32;
        short8 a0 = *(const short8*)&ab[(0 * 16 + lo) * FP + ko + hi * 8];
        short8 a1 = *(const short8*)&ab[(1 * 16 + lo) * FP + ko + hi * 8];
        acc0 = __builtin_amdgcn_mfma_f32_16x16x32_bf16(a0, bf, acc0, 0, 0, 0);
        acc1 = __builtin_amdgcn_mfma_f32_16x16x32_bf16(a1, bf, acc1, 0, 0, 0);
    }

    // epilogue: + (1-beta)(f+f0) + bias, relu; oS = bf16(q*ns); optional h write (fp32)
    int colg = wv * 16 + lo;
    float bv = bias[colg];
#pragma unroll
    for (int m = 0; m < 2; ++m) {
        f32x4v a = m ? acc1 : acc0;
#pragma unroll
        for (int r = 0; r < 4; ++r) {
            int rowl = m * 16 + hi * 4 + r;
            float fv = bfs(fS[rowl * FP + colg]);
            float f0v = bfs(f0S[rowl * FP + colg]);
            float q = fmaxf(a[r] + omb * (fv + f0v) + bv, 0.0f);
            oS[rowl * FP + colg] = (unsigned short)f2bf(q * nsS[rowl]);
            if (write_h) {
                int node = nb + rowl;
                if (node < NN) h[(size_t)node * HID + colg] = q;
            }
        }
    }
    __syncthreads();

    // coalesced hs_out write: thread i -> node i>>3, 16B segment i&7
    {
        int nl = tid >> 3, sg = tid & 7;
        int node = nb + nl;
        if (node < NN) {
            uint4 v = *(const uint4*)&oS[nl * FP + sg * 8];
            *(uint4*)(hs_out + (size_t)node * 32 + sg * 4) = v;
        }
    }
}

// ---------------- output: block = 128 nodes; wave pair splits the 40 cols; LDS lse reduce ----------------
__global__ __launch_bounds__(256) void k_out(const float* __restrict__ h, const float* __restrict__ Wout,
                                             const float* __restrict__ bout, float* __restrict__ out) {
    __shared__ float red_mx[4][64];
    __shared__ float red_s[4][64];
    int tid = threadIdx.x;
    int lane = tid & 63;
    int wv = tid >> 6;
    int half = wv & 1;
    int grp = wv >> 1;
    int node = blockIdx.x * 128 + grp * 64 + lane;
    int nodec = min(node, NN - 1);
    float acc[20];
#pragma unroll
    for (int c = 0; c < 20; c++) acc[c] = 0.0f;
    const float4* hr = (const float4*)(h + (size_t)nodec * HID);
    const float* wb = Wout + half * 20;
    for (int kk = 0; kk < HID / 4; ++kk) {
        float4 a = hr[kk];
        float av[4] = {a.x, a.y, a.z, a.w};
#pragma unroll
        for (int j = 0; j < 4; j++) {
            const float* wr = wb + (size_t)(kk * 4 + j) * OUTF;
#pragma unroll
            for (int c = 0; c < 20; c++) acc[c] += av[j] * wr[c];
        }
    }
    const float* bp = bout + half * 20;
#pragma unroll
    for (int c = 0; c < 20; c++) acc[c] += bp[c];
    float mx = acc[0];
#pragma unroll
    for (int c = 1; c < 20; c++) mx = fmaxf(mx, acc[c]);
    red_mx[wv][lane] = mx;
    __syncthreads();
    float gmx = fmaxf(mx, red_mx[wv ^ 1][lane]);
    float s = 0.0f;
#pragma unroll
    for (int c = 0; c < 20; c++) s += expf(acc[c] - gmx);
    red_s[wv][lane] = s;
    __syncthreads();
    float lse = logf(s + red_s[wv ^ 1][lane]) + gmx;
    if (node < NN) {
        float4* op = (float4*)(out + (size_t)node * OUTF + half * 20);
#pragma unroll
        for (int q = 0; q < 5; q++) {
            float4 v;
            v.x = acc[q * 4 + 0] - lse;
            v.y = acc[q * 4 + 1] - lse;
            v.z = acc[q * 4 + 2] - lse;
            v.w = acc[q * 4 + 3] - lse;
            op[q] = v;
        }
    }
}

extern "C" void kernel_launch(void* const* d_in, const int* in_sizes, int n_in,
                              void* d_out, int out_size, void* d_ws, size_t ws_size,
                              hipStream_t stream) {
    const float* feat = (const float*)d_in[0];
    const float* Win  = (const float*)d_in[1];
    const float* bin  = (const float*)d_in[2];
    const float* W1   = (const float*)d_in[3];
    const float* W2   = (const float*)d_in[4];
    const float* bvec = (const float*)d_in[5];
    const float* Wout = (const float*)d_in[6];
    const float* bout = (const float*)d_in[7];
    const int*   src  = (const int*)d_in[8];
    const int*   dst  = (const int*)d_in[9];
    float* out = (float*)d_out;

    char* ws = (char*)d_ws;
    size_t off = 0;
    auto take = [&](size_t bytes) {
        void* p = ws + off;
        off += (bytes + 255) & ~(size_t)255;
        return p;
    };
    int* bsum      = (int*)take(256 * 4);
    int* row_start = (int*)take(NN * 4);
    int* col       = (int*)take(NE * 4);
    float* nsrc    = (float*)take(NN * 4);
    float* ndst    = (float*)take(NN * 4);
    int* cntD      = (int*)take(SLEN * 4);
    int* cntS      = (int*)take(SLEN * 4);
    int* offD      = (int*)take(SLEN * 4);
    int* offS      = (int*)take(SLEN * 4);
    int* sincl     = (int*)take(SLEN * 4);
    unsigned short* wcat  = (unsigned short*)take((size_t)NL * 4 * 4 * 64 * 8 * 2);  // 256 KB bf16 frags
    unsigned short* wfrag = (unsigned short*)take((size_t)INF * HID * 2);
    unsigned int* f0b = (unsigned int*)take((size_t)NN * HID * 2);  // bf16
    float* hbuf    = (float*)take((size_t)NN * HID * 4);            // gemm0 partial p0; edst alias; h
    float* part1   = (float*)take((size_t)NN * HID * 4);            // gemm0 partial p1; esrc alias
    unsigned int* hsA = (unsigned int*)take((size_t)NN * HID * 2);  // bf16
    unsigned int* hsB = (unsigned int*)take((size_t)NN * HID * 2);  // bf16

    // setup-phase aliases (dead before k_gemm0 writes them)
    uint2* edst = (uint2*)hbuf;   // NE * 8B = 6.4 MB <= 12.8 MB
    int* esrc   = (int*)part1;    // NE * 4B = 3.2 MB

    const int NB_W = (NN + 63) / 64;     // 782
    const int NB_L = (NN + TN - 1) / TN; // 1563
    const int NB_O = (NN + 127) / 128;   // 391
    const int NB_S = SLEN / 256;         // 196

    // bucketed CSR build (zero global atomics)
    k_cnt<<<NBLK, 256, 0, stream>>>(src, dst, cntD, cntS);
    gscanA<<<NB_S, 256, 0, stream>>>(cntD, sincl, bsum, SLEN);
    gscanB<<<1, 256, 0, stream>>>(bsum, NB_S);
    gscanC<<<NB_S, 256, 0, stream>>>(sincl, cntD, bsum, offD, SLEN);
    gscanA<<<NB_S, 256, 0, stream>>>(cntS, sincl, bsum, SLEN);
    gscanB<<<1, 256, 0, stream>>>(bsum, NB_S);
    gscanC<<<NB_S, 256, 0, stream>>>(sincl, cntS, bsum, offS, SLEN);
    k_scat<<<NBLK, 256, 0, stream>>>(src, dst, offD, offS, edst, esrc);
    k_bcsr<<<NBUK, 256, 0, stream>>>(edst, offD, ndst, row_start, col);
    k_bns<<<NBUK, 256, 0, stream>>>(esrc, offS, nsrc);

    k_wcat<<<(NL * 4 * 4 * 64 * 8 + 255) / 256, 256, 0, stream>>>(W1, W2, wcat);
    k_wfrag<<<(INF * HID + 255) / 256, 256, 0, stream>>>(Win, wfrag);
    k_gemm0<<<2 * NB_W, 256, 0, stream>>>(feat, wfrag, hbuf, part1);
    k_gfin<<<(NN * 16 + 255) / 256, 256, 0, stream>>>(hbuf, part1, bin, nsrc, hsA, f0b);

    // ping-pong bf16 hs buffers (gathers read arbitrary rows; in-place would race)
    for (int l = 0; l < NL; ++l) {
        const unsigned int* hin = (l & 1) ? hsB : hsA;
        unsigned int* hout = (l & 1) ? hsA : hsB;
        float beta = logf(0.5f / (float)(l + 1) + 1.0f);
        float omb = 1.0f - beta;
        k_layer<<<NB_L, 256, 0, stream>>>(hin, col, row_start, ndst, f0b,
                                          wcat + (size_t)l * 4 * 4 * 64 * 8, bvec + l * HID,
                                          nsrc, omb, hbuf, hout, (l == NL - 1) ? 1 : 0);
    }
    k_out<<<NB_O, 256, 0, stream>>>(hbuf, Wout, bout, out);
}

// Round 9
// 558.075 us; speedup vs baseline: 10.4887x; 1.0372x over previous
//
#include <hip/hip_runtime.h>
#include <math.h>

#define NN 50000
#define NE 800000
#define INF 512
#define HID 64
#define OUTF 40
#define NL 16

// bucketed CSR build parameters
#define NBLK 256      // edge-blocks; NE = NBLK * EPB exactly
#define EPB 3125
#define NBUK 196      // node buckets of 256 (node >> 8); 196*256 = 50176 >= NN
#define SLEN (NBUK * NBLK)  // 50176 count/offset entries per direction

// layer tile
#define TN 32         // nodes per k_layer block
#define FP 72         // LDS row pitch in bf16 (144 B, 16B-aligned)

using short8 = __attribute__((ext_vector_type(8))) short;
using f32x4v = __attribute__((ext_vector_type(4))) float;

// bf16 helpers: RNE pack, cheap unpack
__device__ __forceinline__ unsigned int f2bf(float f) {
    unsigned int u = __float_as_uint(f);
    return (u + 0x7fffu + ((u >> 16) & 1u)) >> 16;
}
__device__ __forceinline__ float bflo(unsigned int w) { return __uint_as_float(w << 16); }
__device__ __forceinline__ float bfhi(unsigned int w) { return __uint_as_float(w & 0xffff0000u); }
__device__ __forceinline__ float bfs(unsigned short u) { return __uint_as_float(((unsigned)u) << 16); }

// ---------------- bucketed CSR build (no global atomics) ----------------

// per-(bucket, edge-block) counts; dst counts in cnt2[0..SLEN), src counts in cnt2[SLEN..2*SLEN)
__global__ __launch_bounds__(256) void k_cnt(const int* __restrict__ src, const int* __restrict__ dst,
                                             int* __restrict__ cnt2) {
    __shared__ int hD[NBUK];
    __shared__ int hS[NBUK];
    int t = threadIdx.x;
    int blk = blockIdx.x;
    if (t < NBUK) { hD[t] = 0; hS[t] = 0; }
    __syncthreads();
    int s0 = blk * EPB;
    for (int i = t; i < EPB; i += 256) {
        int e = s0 + i;
        atomicAdd(&hD[dst[e] >> 8], 1);
        atomicAdd(&hS[src[e] >> 8], 1);
    }
    __syncthreads();
    if (t < NBUK) {
        cnt2[t * NBLK + blk] = hD[t];
        cnt2[SLEN + t * NBLK + blk] = hS[t];
    }
}

// scan trio over the CONCATENATED 2*SLEN array (one chain instead of two)
__global__ __launch_bounds__(256) void gscanA(const int* __restrict__ in, int* __restrict__ incl,
                                              int* __restrict__ bsum, int len) {
    __shared__ int lds[256];
    int i = blockIdx.x * 256 + threadIdx.x;
    int v = (i < len) ? in[i] : 0;
    lds[threadIdx.x] = v;
    __syncthreads();
    for (int off = 1; off < 256; off <<= 1) {
        int t = (threadIdx.x >= off) ? lds[threadIdx.x - off] : 0;
        __syncthreads();
        lds[threadIdx.x] += t;
        __syncthreads();
    }
    if (i < len) incl[i] = lds[threadIdx.x];
    if (threadIdx.x == 255) bsum[blockIdx.x] = lds[255];
}

__global__ __launch_bounds__(512) void gscanB(int* __restrict__ bsum, int nb) {
    __shared__ int lds[512];
    int v = (threadIdx.x < nb) ? bsum[threadIdx.x] : 0;
    lds[threadIdx.x] = v;
    __syncthreads();
    for (int off = 1; off < 512; off <<= 1) {
        int t = (threadIdx.x >= off) ? lds[threadIdx.x - off] : 0;
        __syncthreads();
        lds[threadIdx.x] += t;
        __syncthreads();
    }
    if (threadIdx.x < nb) bsum[threadIdx.x] = lds[threadIdx.x] - v;  // exclusive
}

// exclusive offsets; second half (src direction) rebased by -NE (sum of all dst counts)
__global__ __launch_bounds__(256) void gscanC(const int* __restrict__ incl, const int* __restrict__ in,
                                              const int* __restrict__ bsum, int* __restrict__ off, int len) {
    int i = blockIdx.x * 256 + threadIdx.x;
    if (i < len) off[i] = incl[i] - in[i] + bsum[i >> 8] - ((i >= SLEN) ? NE : 0);
}

__global__ __launch_bounds__(256) void k_scat(const int* __restrict__ src, const int* __restrict__ dst,
                                              const int* __restrict__ offD, const int* __restrict__ offS,
                                              uint2* __restrict__ edst, int* __restrict__ esrc) {
    __shared__ int cD[NBUK];
    __shared__ int cS[NBUK];
    int t = threadIdx.x;
    int blk = blockIdx.x;
    if (t < NBUK) { cD[t] = 0; cS[t] = 0; }
    __syncthreads();
    int s0 = blk * EPB;
    for (int i = t; i < EPB; i += 256) {
        int e = s0 + i;
        int d = dst[e];
        int s = src[e];
        int bD = d >> 8;
        int r = atomicAdd(&cD[bD], 1);
        uint2 v;
        v.x = (unsigned)d;
        v.y = (unsigned)s;
        edst[offD[bD * NBLK + blk] + r] = v;
        int bS = s >> 8;
        int r2 = atomicAdd(&cS[bS], 1);
        esrc[offS[bS * NBLK + blk] + r2] = s;
    }
}

// merged: blocks [0,NBUK) build dst-side CSR (nd, row_start, col); blocks [NBUK,2*NBUK) build ns
__global__ __launch_bounds__(256) void k_build(const uint2* __restrict__ edst, const int* __restrict__ esrc,
                                               const int* __restrict__ offD, const int* __restrict__ offS,
                                               float* __restrict__ nd, int* __restrict__ row_start,
                                               int* __restrict__ col, float* __restrict__ ns) {
    __shared__ int cnt[256];
    __shared__ int ex[256];
    __shared__ int cur[256];
    int t = threadIdx.x;
    if (blockIdx.x < NBUK) {
        int b = blockIdx.x;
        int base = offD[b * NBLK];
        int end = (b < NBUK - 1) ? offD[(b + 1) * NBLK] : NE;
        cnt[t] = 0;
        __syncthreads();
        for (int p = base + t; p < end; p += 256) {
            uint2 ed = edst[p];
            atomicAdd(&cnt[ed.x & 255], 1);
        }
        __syncthreads();
        int v = cnt[t];
        ex[t] = v;
        __syncthreads();
        for (int off = 1; off < 256; off <<= 1) {
            int tv = (t >= off) ? ex[t - off] : 0;
            __syncthreads();
            ex[t] += tv;
            __syncthreads();
        }
        int excl = ex[t] - v;
        cur[t] = excl;
        int node = b * 256 + t;
        if (node < NN) {
            nd[node] = 1.0f / sqrtf((float)max(v, 1));
            row_start[node] = base + excl;
        }
        __syncthreads();
        for (int p = base + t; p < end; p += 256) {
            uint2 ed = edst[p];
            int r = atomicAdd(&cur[ed.x & 255], 1);
            col[base + r] = (int)ed.y;
        }
    } else {
        int b = blockIdx.x - NBUK;
        int base = offS[b * NBLK];
        int end = (b < NBUK - 1) ? offS[(b + 1) * NBLK] : NE;
        cnt[t] = 0;
        __syncthreads();
        for (int p = base + t; p < end; p += 256) {
            atomicAdd(&cnt[esrc[p] & 255], 1);
        }
        __syncthreads();
        int node = b * 256 + t;
        if (node < NN) ns[node] = 1.0f / sqrtf((float)max(cnt[t], 1));
    }
}

// ---------------- weight prep (merged): layer weights + Win fragments ----------------
// wc layout [l][s(4)][c(4)][lane(64)][j(8)], beta-scaled bf16, combined K=128 ([W1;W2]).
// wf layout [s(16)][c(4)][lane(64)][j(8)] for the h0 GEMM.
__global__ __launch_bounds__(256) void k_wpp(const float* __restrict__ W1, const float* __restrict__ W2,
                                             const float* __restrict__ Win,
                                             unsigned short* __restrict__ wc, unsigned short* __restrict__ wf) {
    int o = blockIdx.x * 256 + threadIdx.x;
    const int NWC = NL * 4 * 4 * 64 * 8;  // 131072
    if (o < NWC) {
        int j = o & 7;
        int ln = (o >> 3) & 63;
        int c = (o >> 9) & 3;
        int s = (o >> 11) & 3;
        int l = o >> 13;
        int colg = c * 16 + (ln & 15);
        int k = (s & 1) * 32 + ((ln >> 4) << 3) + j;
        float beta = logf(0.5f / (float)(l + 1) + 1.0f);
        const float* W = (s < 2) ? W1 : W2;
        wc[o] = (unsigned short)f2bf(beta * W[((size_t)l * 64 + k) * 64 + colg]);
    } else if (o < NWC + 16 * 4 * 64 * 8) {
        int o2 = o - NWC;
        int jj = o2 & 7;
        int l = (o2 >> 3) & 63;
        int c = (o2 >> 9) & 3;
        int s = o2 >> 11;
        int colg = c * 16 + (l & 15);
        int k = s * 32 + ((l >> 4) << 3) + jj;
        wf[o2] = (unsigned short)f2bf(Win[k * HID + colg]);
    }
}

// ---------------- h0 GEMM: bf16 MFMA (16x16x32), fragment-ordered LDS, K-split x2 ----------------
__global__ __launch_bounds__(256) void k_gemm0(const float* __restrict__ feat, const unsigned short* __restrict__ wf,
                                               float* __restrict__ p0, float* __restrict__ p1) {
    __shared__ unsigned int fS[2048];  // 8 KB: [s(2)][w(4)][lane(64)][4 uints = 8 bf16]
    int tid = threadIdx.x;
    int lane = tid & 63;
    int wv = tid >> 6;
    int bx = blockIdx.x;
    int w = bx >> 1;
    int kh = bx & 1;
    int nb = w * 64;
    f32x4v acc[4];
#pragma unroll
    for (int c = 0; c < 4; c++) acc[c] = {0.0f, 0.0f, 0.0f, 0.0f};

    int k0 = kh * 256;
    for (int kc = k0; kc < k0 + 256; kc += 64) {
        if (kc != k0) __syncthreads();
        float4 t[4];
#pragma unroll
        for (int j = 0; j < 4; j++) {
            int i = tid + j * 256;
            int nl = i >> 4;
            int k4 = i & 15;
            int n = min(nb + nl, NN - 1);
            t[j] = *(const float4*)(feat + (size_t)n * INF + kc + k4 * 4);
        }
#pragma unroll
        for (int j = 0; j < 4; j++) {
            int i = tid + j * 256;
            int nl = i >> 4;
            int kl = (i & 15) * 4;
            int s = kl >> 5;
            int kk = kl & 31;
            int lslot = (nl & 15) | ((kk >> 3) << 4);
            int dstu = (((s * 4 + (nl >> 4)) * 64 + lslot) << 2) + ((kk & 4) >> 1);
            fS[dstu] = f2bf(t[j].x) | (f2bf(t[j].y) << 16);
            fS[dstu + 1] = f2bf(t[j].z) | (f2bf(t[j].w) << 16);
        }
        __syncthreads();
#pragma unroll
        for (int s = 0; s < 2; ++s) {
            int sg = (kc + s * 32) >> 5;
            short8 af = *(const short8*)&fS[((s * 4 + wv) * 64 + lane) << 2];
            short8 bf[4];
#pragma unroll
            for (int c = 0; c < 4; ++c)
                bf[c] = *(const short8*)(wf + ((size_t)(sg * 4 + c) * 64 + lane) * 8);
#pragma unroll
            for (int c = 0; c < 4; ++c)
                acc[c] = __builtin_amdgcn_mfma_f32_16x16x32_bf16(af, bf[c], acc[c], 0, 0, 0);
        }
    }
    float* p = kh ? p1 : p0;
    int nodeb = nb + (wv << 4) + ((lane >> 4) << 2);
    int colb = lane & 15;
#pragma unroll
    for (int r = 0; r < 4; ++r) {
        int node = nodeb + r;
        if (node < NN) {
            float* pp = p + (size_t)node * HID + colb;
#pragma unroll
            for (int c = 0; c < 4; ++c) pp[c * 16] = acc[c][r];
        }
    }
}

// combine: p0+p1, +bias, relu, ns-scale, bf16 pack -> hs, f0b
__global__ __launch_bounds__(256) void k_gfin(const float* __restrict__ p0, const float* __restrict__ p1,
                                              const float* __restrict__ bin, const float* __restrict__ ns,
                                              unsigned int* __restrict__ hs, unsigned int* __restrict__ f0b) {
    int i = blockIdx.x * 256 + threadIdx.x;
    if (i >= NN * 16) return;
    int node = i >> 4;
    int q = i & 15;
    float4 a = ((const float4*)p0)[i];
    float4 b = ((const float4*)p1)[i];
    float4 bi = ((const float4*)bin)[q];
    float nsv = ns[node];
    float q0 = fmaxf(a.x + b.x + bi.x, 0.0f);
    float q1 = fmaxf(a.y + b.y + bi.y, 0.0f);
    float q2 = fmaxf(a.z + b.z + bi.z, 0.0f);
    float q3 = fmaxf(a.w + b.w + bi.w, 0.0f);
    uint2 pk;
    pk.x = f2bf(q0 * nsv) | (f2bf(q1 * nsv) << 16);
    pk.y = f2bf(q2 * nsv) | (f2bf(q3 * nsv) << 16);
    *(uint2*)(hs + (size_t)node * 32 + q * 2) = pk;
    uint2 pf;
    pf.x = f2bf(q0 * 0.1f) | (f2bf(q1 * 0.1f) << 16);
    pf.y = f2bf(q2 * 0.1f) | (f2bf(q3 * 0.1f) << 16);
    *(uint2*)(f0b + (size_t)node * 32 + q * 2) = pf;
}

// ---------------- fused layer: pair-gather agg (uint4, 8 edges/instr) + MFMA matmul ----------------
// 256 threads = 4 waves, 32-node tile. 16-lane group per node; within a group, lanes ql<8 own the
// EVEN edges' full 128B rows (16B each), lanes ql>=8 the ODD edges' -> one wave-gather covers
// 8 edges (vs 4 with uint2). Per-lane fp32 accum of dims [8(ql&7), +8); __shfl_xor(8) merges
// even/odd partials (reassociation only). Then K=128 MFMA + fp32 identity epilogue (R8 structure).
__global__ __launch_bounds__(256) void k_layer(const unsigned int* __restrict__ hs_in, const int* __restrict__ col,
                                               const int* __restrict__ row_start,
                                               const float* __restrict__ nd, const unsigned int* __restrict__ f0b,
                                               const unsigned short* __restrict__ wc, const float* __restrict__ bias,
                                               const float* __restrict__ ns, float omb,
                                               float* __restrict__ h, unsigned int* __restrict__ hs_out, int write_h) {
    __shared__ unsigned short fS[TN * FP];   // agg f (scaled 0.9*nd), bf16
    __shared__ unsigned short f0S[TN * FP];  // f0, bf16
    __shared__ unsigned short oS[TN * FP];   // output bounce
    __shared__ float nsS[TN];
    int tid = threadIdx.x;
    int lane = tid & 63;
    int wv = tid >> 6;   // 0..3
    int nb = blockIdx.x * TN;
    int g = lane >> 4;   // group-in-wave 0..3
    int ql = lane & 15;
    int half = ql >> 3;  // 0: even edges, 1: odd edges
    int qb = ql & 7;     // 16B segment: dims [8qb, 8qb+8)

    // stage f0 tile: thread i -> node i>>3, 16B segment i&7
    {
        int nl = tid >> 3, sg = tid & 7;
        int n = min(nb + nl, NN - 1);
        uint4 v = *(const uint4*)(f0b + (size_t)n * 32 + sg * 4);
        *(uint4*)&f0S[nl * FP + sg * 8] = v;
    }
    if (tid < TN) nsS[tid] = ns[min(nb + tid, NN - 1)];

    // hoist both passes' metadata + first-chunk col indices
    int nlP[2], baseP[2], degP[2], idxP[2];
    float ndP[2];
#pragma unroll
    for (int p = 0; p < 2; ++p) {
        int nl = p * 16 + wv * 4 + g;
        int n = min(nb + nl, NN - 1);
        nlP[p] = nl;
        int base = row_start[n];
        int nxt = (n < NN - 1) ? row_start[n + 1] : NE;
        baseP[p] = base;
        degP[p] = nxt - base;
        ndP[p] = nd[n];
    }
#pragma unroll
    for (int p = 0; p < 2; ++p) {
        idxP[p] = (ql < min(16, degP[p])) ? col[baseP[p] + ql] : 0;
    }

    // pair-gather aggregation
#pragma unroll
    for (int pass = 0; pass < 2; ++pass) {
        int base = baseP[pass];
        int deg = degP[pass];
        int idxv = idxP[pass];
        float a0 = 0.f, a1 = 0.f, a2 = 0.f, a3 = 0.f, a4 = 0.f, a5 = 0.f, a6 = 0.f, a7 = 0.f;
        for (int done = 0; done < deg; done += 16) {
            int cnt = min(16, deg - done);
            int nxt = done + 16;
            int idxn = 0;
            if (nxt < deg && ql < deg - nxt) idxn = col[base + nxt + ql];
            uint4 pv[4];
#pragma unroll
            for (int e = 0; e < 4; ++e) {
                int ec = 2 * e + half;
                int s = __shfl(idxv, (g << 4) | ec, 64);
                uint4 v = {0u, 0u, 0u, 0u};
                if (ec < cnt) v = *(const uint4*)(hs_in + (size_t)s * 32 + qb * 4);
                pv[e] = v;
            }
#pragma unroll
            for (int e = 0; e < 4; ++e) {
                a0 += bflo(pv[e].x); a1 += bfhi(pv[e].x);
                a2 += bflo(pv[e].y); a3 += bfhi(pv[e].y);
                a4 += bflo(pv[e].z); a5 += bfhi(pv[e].z);
                a6 += bflo(pv[e].w); a7 += bfhi(pv[e].w);
            }
#pragma unroll
            for (int e = 0; e < 4; ++e) {
                int ec = 8 + 2 * e + half;
                int s = __shfl(idxv, (g << 4) | ec, 64);
                uint4 v = {0u, 0u, 0u, 0u};
                if (ec < cnt) v = *(const uint4*)(hs_in + (size_t)s * 32 + qb * 4);
                pv[e] = v;
            }
#pragma unroll
            for (int e = 0; e < 4; ++e) {
                a0 += bflo(pv[e].x); a1 += bfhi(pv[e].x);
                a2 += bflo(pv[e].y); a3 += bfhi(pv[e].y);
                a4 += bflo(pv[e].z); a5 += bfhi(pv[e].z);
                a6 += bflo(pv[e].w); a7 += bfhi(pv[e].w);
            }
            idxv = idxn;
        }
        // merge even/odd partials across ql^8 (same dims on both lanes)
        a0 += __shfl_xor(a0, 8, 64);
        a1 += __shfl_xor(a1, 8, 64);
        a2 += __shfl_xor(a2, 8, 64);
        a3 += __shfl_xor(a3, 8, 64);
        a4 += __shfl_xor(a4, 8, 64);
        a5 += __shfl_xor(a5, 8, 64);
        a6 += __shfl_xor(a6, 8, 64);
        a7 += __shfl_xor(a7, 8, 64);
        float sc = 0.9f * ndP[pass];
        int nl = nlP[pass];
        if (half == 0) {
            uint4 w;
            w.x = f2bf(a0 * sc) | (f2bf(a1 * sc) << 16);
            w.y = f2bf(a2 * sc) | (f2bf(a3 * sc) << 16);
            w.z = f2bf(a4 * sc) | (f2bf(a5 * sc) << 16);
            w.w = f2bf(a6 * sc) | (f2bf(a7 * sc) << 16);
            *(uint4*)&fS[nl * FP + qb * 8] = w;
        }
    }
    __syncthreads();

    // MFMA: wave wv owns col-tile wv; m-tiles = node halves; K=128 = 4 steps ([f;f0] x [W1;W2])
    int hi = lane >> 4;
    int lo = lane & 15;
    f32x4v acc0 = {0.0f, 0.0f, 0.0f, 0.0f};
    f32x4v acc1 = {0.0f, 0.0f, 0.0f, 0.0f};
#pragma unroll
    for (int s = 0; s < 4; ++s) {
        short8 bf = *(const short8*)(wc + ((size_t)(s * 4 + wv) * 64 + lane) * 8);
        const unsigned short* ab = (s < 2) ? fS : f0S;
        int ko = (s & 1) * 32;
        short8 a0 = *(const short8*)&ab[(0 * 16 + lo) * FP + ko + hi * 8];
        short8 a1 = *(const short8*)&ab[(1 * 16 + lo) * FP + ko + hi * 8];
        acc0 = __builtin_amdgcn_mfma_f32_16x16x32_bf16(a0, bf, acc0, 0, 0, 0);
        acc1 = __builtin_amdgcn_mfma_f32_16x16x32_bf16(a1, bf, acc1, 0, 0, 0);
    }

    // epilogue: + (1-beta)(f+f0) + bias, relu; oS = bf16(q*ns); optional h write (fp32)
    int colg = wv * 16 + lo;
    float bv = bias[colg];
#pragma unroll
    for (int m = 0; m < 2; ++m) {
        f32x4v a = m ? acc1 : acc0;
#pragma unroll
        for (int r = 0; r < 4; ++r) {
            int rowl = m * 16 + hi * 4 + r;
            float fv = bfs(fS[rowl * FP + colg]);
            float f0v = bfs(f0S[rowl * FP + colg]);
            float q = fmaxf(a[r] + omb * (fv + f0v) + bv, 0.0f);
            oS[rowl * FP + colg] = (unsigned short)f2bf(q * nsS[rowl]);
            if (write_h) {
                int node = nb + rowl;
                if (node < NN) h[(size_t)node * HID + colg] = q;
            }
        }
    }
    __syncthreads();

    // coalesced hs_out write: thread i -> node i>>3, 16B segment i&7
    {
        int nl = tid >> 3, sg = tid & 7;
        int node = nb + nl;
        if (node < NN) {
            uint4 v = *(const uint4*)&oS[nl * FP + sg * 8];
            *(uint4*)(hs_out + (size_t)node * 32 + sg * 4) = v;
        }
    }
}

// ---------------- output: block = 128 nodes; wave pair splits the 40 cols; LDS lse reduce ----------------
__global__ __launch_bounds__(256) void k_out(const float* __restrict__ h, const float* __restrict__ Wout,
                                             const float* __restrict__ bout, float* __restrict__ out) {
    __shared__ float red_mx[4][64];
    __shared__ float red_s[4][64];
    int tid = threadIdx.x;
    int lane = tid & 63;
    int wv = tid >> 6;
    int half = wv & 1;
    int grp = wv >> 1;
    int node = blockIdx.x * 128 + grp * 64 + lane;
    int nodec = min(node, NN - 1);
    float acc[20];
#pragma unroll
    for (int c = 0; c < 20; c++) acc[c] = 0.0f;
    const float4* hr = (const float4*)(h + (size_t)nodec * HID);
    const float* wb = Wout + half * 20;
    for (int kk = 0; kk < HID / 4; ++kk) {
        float4 a = hr[kk];
        float av[4] = {a.x, a.y, a.z, a.w};
#pragma unroll
        for (int j = 0; j < 4; j++) {
            const float* wr = wb + (size_t)(kk * 4 + j) * OUTF;
#pragma unroll
            for (int c = 0; c < 20; c++) acc[c] += av[j] * wr[c];
        }
    }
    const float* bp = bout + half * 20;
#pragma unroll
    for (int c = 0; c < 20; c++) acc[c] += bp[c];
    float mx = acc[0];
#pragma unroll
    for (int c = 1; c < 20; c++) mx = fmaxf(mx, acc[c]);
    red_mx[wv][lane] = mx;
    __syncthreads();
    float gmx = fmaxf(mx, red_mx[wv ^ 1][lane]);
    float s = 0.0f;
#pragma unroll
    for (int c = 0; c < 20; c++) s += expf(acc[c] - gmx);
    red_s[wv][lane] = s;
    __syncthreads();
    float lse = logf(s + red_s[wv ^ 1][lane]) + gmx;
    if (node < NN) {
        float4* op = (float4*)(out + (size_t)node * OUTF + half * 20);
#pragma unroll
        for (int q = 0; q < 5; q++) {
            float4 v;
            v.x = acc[q * 4 + 0] - lse;
            v.y = acc[q * 4 + 1] - lse;
            v.z = acc[q * 4 + 2] - lse;
            v.w = acc[q * 4 + 3] - lse;
            op[q] = v;
        }
    }
}

extern "C" void kernel_launch(void* const* d_in, const int* in_sizes, int n_in,
                              void* d_out, int out_size, void* d_ws, size_t ws_size,
                              hipStream_t stream) {
    const float* feat = (const float*)d_in[0];
    const float* Win  = (const float*)d_in[1];
    const float* bin  = (const float*)d_in[2];
    const float* W1   = (const float*)d_in[3];
    const float* W2   = (const float*)d_in[4];
    const float* bvec = (const float*)d_in[5];
    const float* Wout = (const float*)d_in[6];
    const float* bout = (const float*)d_in[7];
    const int*   src  = (const int*)d_in[8];
    const int*   dst  = (const int*)d_in[9];
    float* out = (float*)d_out;

    char* ws = (char*)d_ws;
    size_t off = 0;
    auto take = [&](size_t bytes) {
        void* p = ws + off;
        off += (bytes + 255) & ~(size_t)255;
        return p;
    };
    int* bsum      = (int*)take(512 * 4);
    int* row_start = (int*)take(NN * 4);
    int* col       = (int*)take(NE * 4);
    float* nsrc    = (float*)take(NN * 4);
    float* ndst    = (float*)take(NN * 4);
    int* cnt2      = (int*)take(2 * SLEN * 4);   // [cntD | cntS]
    int* off2      = (int*)take(2 * SLEN * 4);   // [offD | offS]
    int* sincl     = (int*)take(2 * SLEN * 4);
    unsigned short* wcat  = (unsigned short*)take((size_t)NL * 4 * 4 * 64 * 8 * 2);  // 256 KB bf16 frags
    unsigned short* wfrag = (unsigned short*)take((size_t)INF * HID * 2);
    unsigned int* f0b = (unsigned int*)take((size_t)NN * HID * 2);  // bf16
    float* hbuf    = (float*)take((size_t)NN * HID * 4);            // gemm0 partial p0; edst alias; h
    float* part1   = (float*)take((size_t)NN * HID * 4);            // gemm0 partial p1; esrc alias
    unsigned int* hsA = (unsigned int*)take((size_t)NN * HID * 2);  // bf16
    unsigned int* hsB = (unsigned int*)take((size_t)NN * HID * 2);  // bf16

    // setup-phase aliases (dead before k_gemm0 writes them)
    uint2* edst = (uint2*)hbuf;   // NE * 8B = 6.4 MB <= 12.8 MB
    int* esrc   = (int*)part1;    // NE * 4B = 3.2 MB
    int* offD = off2;
    int* offS = off2 + SLEN;

    const int NB_W = (NN + 63) / 64;     // 782
    const int NB_L = (NN + TN - 1) / TN; // 1563
    const int NB_O = (NN + 127) / 128;   // 391
    const int NB_S2 = 2 * SLEN / 256;    // 392

    // bucketed CSR build (zero global atomics), single concatenated scan chain
    k_cnt<<<NBLK, 256, 0, stream>>>(src, dst, cnt2);
    gscanA<<<NB_S2, 256, 0, stream>>>(cnt2, sincl, bsum, 2 * SLEN);
    gscanB<<<1, 512, 0, stream>>>(bsum, NB_S2);
    gscanC<<<NB_S2, 256, 0, stream>>>(sincl, cnt2, bsum, off2, 2 * SLEN);
    k_scat<<<NBLK, 256, 0, stream>>>(src, dst, offD, offS, edst, esrc);
    k_build<<<2 * NBUK, 256, 0, stream>>>(edst, esrc, offD, offS, ndst, row_start, col, nsrc);

    k_wpp<<<(NL * 4 * 4 * 64 * 8 + INF * HID + 255) / 256, 256, 0, stream>>>(W1, W2, Win, wcat, wfrag);
    k_gemm0<<<2 * NB_W, 256, 0, stream>>>(feat, wfrag, hbuf, part1);
    k_gfin<<<(NN * 16 + 255) / 256, 256, 0, stream>>>(hbuf, part1, bin, nsrc, hsA, f0b);

    // ping-pong bf16 hs buffers (gathers read arbitrary rows; in-place would race)
    for (int l = 0; l < NL; ++l) {
        const unsigned int* hin = (l & 1) ? hsB : hsA;
        unsigned int* hout = (l & 1) ? hsA : hsB;
        float beta = logf(0.5f / (float)(l + 1) + 1.0f);
        float omb = 1.0f - beta;
        k_layer<<<NB_L, 256, 0, stream>>>(hin, col, row_start, ndst, f0b,
                                          wcat + (size_t)l * 4 * 4 * 64 * 8, bvec + l * HID,
                                          nsrc, omb, hbuf, hout, (l == NL - 1) ? 1 : 0);
    }
    k_out<<<NB_O, 256, 0, stream>>>(hbuf, Wout, bout, out);
}